// Round 11
// baseline (297.450 us; speedup 1.0000x reference)
//
#include <hip/hip_runtime.h>
#include <hip/hip_bf16.h>
#include <math.h>

#define H_DIM 1024
#define SEQ   2048
#define BATCH 2
#define NHEAD 16
#define DKV   64
#define ROWS  (BATCH*SEQ)   // 4096

typedef __attribute__((ext_vector_type(8))) short short8;
typedef __attribute__((ext_vector_type(4))) float f32x4;

static __device__ __forceinline__ unsigned short f32_bf16(float f) {
    unsigned int u = __builtin_bit_cast(unsigned int, f);
    u += 0x7FFF + ((u >> 16) & 1);          // RNE
    return (unsigned short)(u >> 16);
}

// A&S 7.1.26 rational-poly erf, |err| < 1.5e-7
static __device__ __forceinline__ float fast_erf(float x) {
    float ax = fabsf(x);
    float t = 1.0f / fmaf(0.3275911f, ax, 1.0f);
    float p = t * fmaf(t, fmaf(t, fmaf(t, fmaf(t, 1.061405429f, -1.453152027f),
                                       1.421413741f), -0.284496736f), 0.254829592f);
    float y = fmaf(-p, __expf(-ax * ax), 1.0f);
    return copysignf(y, x);
}

static __device__ __forceinline__ void gload16(const unsigned short* g, unsigned short* l) {
    __builtin_amdgcn_global_load_lds(
        (const __attribute__((address_space(1))) void*)g,
        (__attribute__((address_space(3))) void*)l,
        16, 0, 0);
}

// ---------------- fp32 [K][N] -> bf16 [N][K] transpose ----------------
__global__ __launch_bounds__(256) void transpose_bf16(const float* __restrict__ in,
                                                      unsigned short* __restrict__ out,
                                                      int K, int N) {
    __shared__ float tile[32][33];
    int n0 = blockIdx.x * 32, k0 = blockIdx.y * 32;
    int tx = threadIdx.x & 31, ty = threadIdx.x >> 5;   // 32 x 8
    #pragma unroll
    for (int i = 0; i < 4; ++i)
        tile[ty + i * 8][tx] = in[(size_t)(k0 + ty + i * 8) * N + n0 + tx];
    __syncthreads();
    #pragma unroll
    for (int i = 0; i < 4; ++i)
        out[(size_t)(n0 + ty + i * 8) * K + k0 + tx] = f32_bf16(tile[tx][ty + i * 8]);
}

// ---------------- LayerNorm (fp32 in -> bf16 out) ----------------
__global__ __launch_bounds__(256) void ln_bf16(const float* __restrict__ x,
                                               const float* __restrict__ w,
                                               const float* __restrict__ bb,
                                               unsigned short* __restrict__ out) {
    int row = blockIdx.x;
    int tid = threadIdx.x;
    float4 v = ((const float4*)(x + (size_t)row * H_DIM))[tid];
    float s  = v.x + v.y + v.z + v.w;
    float s2 = v.x*v.x + v.y*v.y + v.z*v.z + v.w*v.w;
    #pragma unroll
    for (int off = 1; off < 64; off <<= 1) {
        s  += __shfl_xor(s,  off, 64);
        s2 += __shfl_xor(s2, off, 64);
    }
    __shared__ float red[8];
    int wv = tid >> 6;
    if ((tid & 63) == 0) { red[wv] = s; red[4 + wv] = s2; }
    __syncthreads();
    s  = red[0] + red[1] + red[2] + red[3];
    s2 = red[4] + red[5] + red[6] + red[7];
    float mu = s * (1.0f / H_DIM);
    float rs = rsqrtf(s2 * (1.0f / H_DIM) - mu * mu + 1e-5f);
    float4 wv4 = ((const float4*)w)[tid];
    float4 bv4 = ((const float4*)bb)[tid];
    ushort4 o;
    o.x = f32_bf16((v.x - mu) * rs * wv4.x + bv4.x);
    o.y = f32_bf16((v.y - mu) * rs * wv4.y + bv4.y);
    o.z = f32_bf16((v.z - mu) * rs * wv4.z + bv4.z);
    o.w = f32_bf16((v.w - mu) * rs * wv4.w + bv4.w);
    ((ushort4*)(out + (size_t)row * H_DIM))[tid] = o;
}

// ======== epilogue helper ========
template<int EPI>
static __device__ __forceinline__ void epi_store(f32x4 a, int row0, int col, int N,
                                                 const float* __restrict__ bias,
                                                 const float* __restrict__ resid,
                                                 float* __restrict__ outF,
                                                 unsigned short* __restrict__ outH,
                                                 unsigned short* __restrict__ outH2) {
    float bv = bias[col];
    if (EPI == 4 && col >= 2048) {
        int bb = row0 >> 11, ss = row0 & 2047;
        int hd = col - 2048;
        ushort4 u;
        u.x = f32_bf16(a[0] + bv);
        u.y = f32_bf16(a[1] + bv);
        u.z = f32_bf16(a[2] + bv);
        u.w = f32_bf16(a[3] + bv);
        *(ushort4*)&outH2[((size_t)bb * 1024 + hd) * SEQ + ss] = u;
    } else {
        #pragma unroll
        for (int j = 0; j < 4; ++j) {
            int row = row0 + j;
            size_t idx = (size_t)row * N + col;
            float c = a[j] + bv;
            if (EPI == 0) {
                outF[idx] = c;
            } else if (EPI == 1) {
                outF[idx] = resid[idx] + c;
            } else if (EPI == 2) {
                float g = 0.5f * c * (1.0f + fast_erf(c * 0.70710678118f));
                outH[idx] = f32_bf16(g);
            } else if (EPI == 3) {
                outH[idx] = f32_bf16(c);
            } else {
                outH[(size_t)row * 2048 + col] = f32_bf16(c);   // Q|K packed
            }
        }
    }
}

// ---------------- bf16 MFMA GEMM, 128 x (NI*32) tile, BK=32 (m97 geometry),
//                  single-buffer 2-barrier loop, XCD-chunked flat grid ----------------
// NI=4 -> 128x128 tile (FC/QKV); NI=2 -> 128x64 tile (Wo/Proj: grid 512, 2 blocks/CU).
// LDS chunk swizzle (16B units within a 64B row): phys = logical ^ ((row>>1)&3).
// Both sides: staging pre-swizzles the GLOBAL source; reads XOR the same pattern
// -> ds_read_b128 conflict-free at 64B row stride; gload_lds dest stays linear.
template<int EPI, int NI>
__global__ __launch_bounds__(256) void gemmT(const unsigned short* __restrict__ A,
                                             const unsigned short* __restrict__ Bt,
                                             const float* __restrict__ bias,
                                             const float* __restrict__ resid,
                                             float* __restrict__ outF,
                                             unsigned short* __restrict__ outH,
                                             unsigned short* __restrict__ outH2,
                                             int gx, int N, int K) {
    constexpr int BN = NI * 32;
    __shared__ __attribute__((aligned(16))) unsigned short As[128][32];
    __shared__ __attribute__((aligned(16))) unsigned short Bs[BN][32];
    int tid = threadIdx.x;
    int w = tid >> 6, l = tid & 63;
    int l15 = l & 15, lg = l >> 4;
    int wm = w & 1, wn = w >> 1;

    // bijective XCD-chunk swizzle (all our grids are %8==0)
    int qq = gridDim.x >> 3;
    int wg = (blockIdx.x & 7) * qq + (blockIdx.x >> 3);
    int bm = wg / gx, bn = wg - bm * gx;
    int m0 = bm * 128, n0 = bn * BN;

    f32x4 acc[4][NI] = {};

    // A staging: 512 chunks (8KB), 2 gload16/thread
    const unsigned short* aptr[2];
    unsigned short* lA[2];
    #pragma unroll
    for (int j = 0; j < 2; ++j) {
        int slot = (w * 2 + j) * 64 + l;              // 0..511
        int row = slot >> 2;
        int lc = (slot & 3) ^ ((row >> 1) & 3);       // pre-swizzled source chunk
        aptr[j] = A + (size_t)(m0 + row) * K + lc * 8;
        lA[j] = &As[0][0] + (w * 2 + j) * 512;        // wave-uniform base (+lane*16B HW)
    }
    // B staging: BN*64 chunks, NI/2 gload16/thread
    const unsigned short* bptr[NI / 2];
    unsigned short* lB[NI / 2];
    #pragma unroll
    for (int j = 0; j < NI / 2; ++j) {
        int slot = (w * (NI / 2) + j) * 64 + l;       // 0..BN*4-1
        int row = slot >> 2;
        int lc = (slot & 3) ^ ((row >> 1) & 3);
        bptr[j] = Bt + (size_t)(n0 + row) * K + lc * 8;
        lB[j] = &Bs[0][0] + (w * (NI / 2) + j) * 512;
    }
    // read offsets: row r -> r*32 + (lg ^ ((r>>1)&3))*8 ; (r>>1)&3 == (l15>>1)&3
    int pch = (lg ^ ((l15 >> 1) & 3)) * 8;
    const unsigned short* pA = &As[0][0] + (wm * 64 + l15) * 32 + pch;
    const unsigned short* pB = &Bs[0][0] + (wn * (NI * 16) + l15) * 32 + pch;

    for (int k0 = 0; k0 < K; k0 += 32) {
        __syncthreads();
        #pragma unroll
        for (int j = 0; j < 2; ++j) gload16(aptr[j] + k0, lA[j]);
        #pragma unroll
        for (int j = 0; j < NI / 2; ++j) gload16(bptr[j] + k0, lB[j]);
        __syncthreads();

        short8 af[4], bf[NI];
        #pragma unroll
        for (int mi = 0; mi < 4; ++mi)
            af[mi] = *(const short8*)(pA + mi * 16 * 32);
        #pragma unroll
        for (int ni = 0; ni < NI; ++ni)
            bf[ni] = *(const short8*)(pB + ni * 16 * 32);
        #pragma unroll
        for (int mi = 0; mi < 4; ++mi)
            #pragma unroll
            for (int ni = 0; ni < NI; ++ni)
                acc[mi][ni] = __builtin_amdgcn_mfma_f32_16x16x32_bf16(af[mi], bf[ni], acc[mi][ni], 0, 0, 0);
    }

    #pragma unroll
    for (int mi = 0; mi < 4; ++mi)
        #pragma unroll
        for (int ni = 0; ni < NI; ++ni)
            epi_store<EPI>(acc[mi][ni], m0 + wm * 64 + mi * 16 + lg * 4,
                           n0 + wn * (NI * 16) + ni * 16 + l15, N, bias, resid, outF, outH, outH2);
}

// ---------------- causal flash attention, swapped-operand softmax ----------------
__global__ __launch_bounds__(256) void attn_mfma(const unsigned short* __restrict__ qk,
                                                 const unsigned short* __restrict__ vT,
                                                 unsigned short* __restrict__ out) {
    int bid = blockIdx.x;
    int swz = (bid & 7) * 128 + (bid >> 3);
    int b  = swz >> 9;
    int h  = (swz >> 5) & 15;
    int qt = 31 - (swz & 31);
    int tid = threadIdx.x;
    int w = tid >> 6, l = tid & 63;
    int l15 = l & 15, lg = l >> 4;

    __shared__ __attribute__((aligned(16))) unsigned short Ks[64][72];
    __shared__ __attribute__((aligned(16))) unsigned short Vt[64][72];
    __shared__ __attribute__((aligned(16))) unsigned short Ps[4][16][72];

    int qrow = qt * 64 + w * 16 + l15;
    short8 qf[2];
    {
        const unsigned short* qp = qk + (size_t)(b * SEQ + qrow) * 2048 + h * DKV + lg * 8;
        qf[0] = *(const short8*)qp;
        qf[1] = *(const short8*)(qp + 32);
    }

    int srow = l >> 2;
    int scol = (l & 3) * 16;
    int krow = w * 16 + srow;
    const unsigned short* kbase = qk + (size_t)(b * SEQ + krow) * 2048 + 1024 + h * DKV + scol;
    const unsigned short* vbase = vT + ((size_t)(b * NHEAD + h) * DKV + krow) * SEQ + scol;

    short8 kr0 = *(const short8*)kbase;
    short8 kr1 = *(const short8*)(kbase + 8);
    short8 vr0 = *(const short8*)vbase;
    short8 vr1 = *(const short8*)(vbase + 8);

    float m = -1e30f, lsum = 0.0f;
    f32x4 oacc[4] = {};

    for (int kt = 0; kt <= qt; ++kt) {
        __syncthreads();
        *(short8*)&Ks[krow][scol]     = kr0;
        *(short8*)&Ks[krow][scol + 8] = kr1;
        *(short8*)&Vt[krow][scol]     = vr0;
        *(short8*)&Vt[krow][scol + 8] = vr1;
        __syncthreads();
        if (kt < qt) {
            const unsigned short* kp = kbase + (size_t)(kt + 1) * 64 * 2048;
            const unsigned short* vp = vbase + (kt + 1) * 64;
            kr0 = *(const short8*)kp;
            kr1 = *(const short8*)(kp + 8);
            vr0 = *(const short8*)vp;
            vr1 = *(const short8*)(vp + 8);
        }

        f32x4 sc[4] = {};
        __builtin_amdgcn_s_setprio(1);
        #pragma unroll
        for (int dstep = 0; dstep < 2; ++dstep) {
            #pragma unroll
            for (int st = 0; st < 4; ++st) {
                short8 kf = *(const short8*)&Ks[st * 16 + l15][dstep * 32 + lg * 8];
                sc[st] = __builtin_amdgcn_mfma_f32_16x16x32_bf16(kf, qf[dstep], sc[st], 0, 0, 0);
            }
        }
        __builtin_amdgcn_s_setprio(0);

        bool diag = (kt == qt);
        int klim = w * 16 + l15;
        float pv[4][4];
        float pmax = -1e30f;
        #pragma unroll
        for (int st = 0; st < 4; ++st) {
            #pragma unroll
            for (int j = 0; j < 4; ++j) {
                float s = sc[st][j] * 0.125f;
                if (diag && (st * 16 + lg * 4 + j > klim)) s = -1e30f;
                pv[st][j] = s;
                pmax = fmaxf(pmax, s);
            }
        }
        pmax = fmaxf(pmax, __shfl_xor(pmax, 16, 64));
        pmax = fmaxf(pmax, __shfl_xor(pmax, 32, 64));

        if (!__all(pmax - m <= 8.0f)) {
            float mn = fmaxf(m, pmax);
            float scl = __expf(m - mn);
            lsum *= scl;
            #pragma unroll
            for (int d = 0; d < 4; ++d)
                #pragma unroll
                for (int j = 0; j < 4; ++j)
                    oacc[d][j] *= scl;
            m = mn;
        }

        float ps = 0.0f;
        #pragma unroll
        for (int st = 0; st < 4; ++st) {
            ushort4 u;
            #pragma unroll
            for (int j = 0; j < 4; ++j) {
                float p = __expf(pv[st][j] - m);
                ps += p;
                ((unsigned short*)&u)[j] = f32_bf16(p);
            }
            *(ushort4*)&Ps[w][l15][st * 16 + lg * 4] = u;
        }
        ps += __shfl_xor(ps, 16, 64);
        ps += __shfl_xor(ps, 32, 64);
        lsum += ps;

        __builtin_amdgcn_s_setprio(1);
        #pragma unroll
        for (int ks = 0; ks < 2; ++ks) {
            short8 pf = *(const short8*)&Ps[w][l15][ks * 32 + lg * 8];
            #pragma unroll
            for (int d = 0; d < 4; ++d) {
                short8 vf = *(const short8*)&Vt[d * 16 + l15][ks * 32 + lg * 8];
                oacc[d] = __builtin_amdgcn_mfma_f32_16x16x32_bf16(vf, pf, oacc[d], 0, 0, 0);
            }
        }
        __builtin_amdgcn_s_setprio(0);
    }

    float inv = 1.0f / lsum;
    size_t ob = (size_t)(b * SEQ + qrow) * H_DIM + h * DKV;
    #pragma unroll
    for (int d = 0; d < 4; ++d) {
        ushort4 u;
        #pragma unroll
        for (int j = 0; j < 4; ++j)
            ((unsigned short*)&u)[j] = f32_bf16(oacc[d][j] * inv);
        *(ushort4*)&out[ob + d * 16 + lg * 4] = u;
    }
}

// ---------------- launch ----------------
extern "C" void kernel_launch(void* const* d_in, const int* in_sizes, int n_in,
                              void* d_out, int out_size, void* d_ws, size_t ws_size,
                              hipStream_t stream) {
    const float* x     = (const float*)d_in[0];
    const float* ln1w  = (const float*)d_in[1];
    const float* ln1b  = (const float*)d_in[2];
    const float* Wqkv  = (const float*)d_in[3];
    const float* bqkv  = (const float*)d_in[4];
    const float* Wo    = (const float*)d_in[5];
    const float* bo    = (const float*)d_in[6];
    const float* ln2w  = (const float*)d_in[7];
    const float* ln2b  = (const float*)d_in[8];
    const float* Wfc   = (const float*)d_in[9];
    const float* bfc   = (const float*)d_in[10];
    const float* Wproj = (const float*)d_in[11];
    const float* bproj = (const float*)d_in[12];
    float* out = (float*)d_out;

    char* ws = (char*)d_ws;
    size_t off = 0;
    auto take = [&](size_t bytes) {
        void* p = ws + off;
        off += (bytes + 255) & ~(size_t)255;
        return p;
    };

    unsigned short* WqT  = (unsigned short*)take((size_t)3072 * 1024 * 2);
    unsigned short* WoT  = (unsigned short*)take((size_t)1024 * 1024 * 2);
    unsigned short* WfcT = (unsigned short*)take((size_t)4096 * 1024 * 2);
    unsigned short* WpT  = (unsigned short*)take((size_t)1024 * 4096 * 2);
    unsigned short* xn1   = (unsigned short*)take((size_t)ROWS * 1024 * 2);
    unsigned short* qk_h  = (unsigned short*)take((size_t)ROWS * 2048 * 2);
    unsigned short* vT    = (unsigned short*)take((size_t)ROWS * 1024 * 2);
    unsigned short* attn  = (unsigned short*)take((size_t)ROWS * 1024 * 2);
    float*          x1    = (float*)take((size_t)ROWS * 1024 * 4);
    unsigned short* xn2   = (unsigned short*)take((size_t)ROWS * 1024 * 2);
    unsigned short* hbuf  = (unsigned short*)take((size_t)ROWS * 4096 * 2);

    // weight transposes fp32[K][N] -> bf16[N][K]
    transpose_bf16<<<dim3(3072 / 32, 1024 / 32), 256, 0, stream>>>(Wqkv,  WqT,  1024, 3072);
    transpose_bf16<<<dim3(1024 / 32, 1024 / 32), 256, 0, stream>>>(Wo,    WoT,  1024, 1024);
    transpose_bf16<<<dim3(4096 / 32, 1024 / 32), 256, 0, stream>>>(Wfc,   WfcT, 1024, 4096);
    transpose_bf16<<<dim3(1024 / 32, 4096 / 32), 256, 0, stream>>>(Wproj, WpT,  4096, 1024);

    // LN1 -> xn1 (bf16)
    ln_bf16<<<ROWS, 256, 0, stream>>>(x, ln1w, ln1b, xn1);

    // QKV: Q|K -> qk_h packed, V -> vT transposed   (128x128, grid 24x32=768)
    gemmT<4, 4><<<768, 256, 0, stream>>>(xn1, WqT, bqkv, nullptr, nullptr, qk_h, vT, 24, 3072, 1024);

    // causal attention -> attn (bf16)
    attn_mfma<<<1024, 256, 0, stream>>>(qk_h, vT, attn);

    // x1 = x + attn @ Wo + bo   (128x64, grid 16x32=512 -> 2 blocks/CU)
    gemmT<1, 2><<<512, 256, 0, stream>>>(attn, WoT, bo, x, x1, nullptr, nullptr, 16, 1024, 1024);

    // LN2 -> xn2 (bf16)
    ln_bf16<<<ROWS, 256, 0, stream>>>(x1, ln2w, ln2b, xn2);

    // h = gelu(xn2 @ Wfc + bfc)   (128x128, grid 32x32=1024)
    gemmT<2, 4><<<1024, 256, 0, stream>>>(xn2, WfcT, bfc, nullptr, nullptr, hbuf, nullptr, 32, 4096, 1024);

    // out = x1 + h @ Wproj + bproj   (128x64, grid 16x32=512)
    gemmT<1, 2><<<512, 256, 0, stream>>>(hbuf, WpT, bproj, x1, out, nullptr, nullptr, 16, 1024, 4096);
}

// Round 12
// 278.262 us; speedup vs baseline: 1.0690x; 1.0690x over previous
//
#include <hip/hip_runtime.h>
#include <hip/hip_bf16.h>
#include <math.h>

#define H_DIM 1024
#define SEQ   2048
#define BATCH 2
#define NHEAD 16
#define DKV   64
#define ROWS  (BATCH*SEQ)   // 4096
#define QSCALE 0.18033688f  // 0.125 * log2(e): scores land in log2 domain

typedef __attribute__((ext_vector_type(8))) short short8;
typedef __attribute__((ext_vector_type(4))) float f32x4;

static __device__ __forceinline__ unsigned short f32_bf16(float f) {
    unsigned int u = __builtin_bit_cast(unsigned int, f);
    u += 0x7FFF + ((u >> 16) & 1);          // RNE
    return (unsigned short)(u >> 16);
}

// A&S 7.1.26 rational-poly erf, |err| < 1.5e-7
static __device__ __forceinline__ float fast_erf(float x) {
    float ax = fabsf(x);
    float t = 1.0f / fmaf(0.3275911f, ax, 1.0f);
    float p = t * fmaf(t, fmaf(t, fmaf(t, fmaf(t, 1.061405429f, -1.453152027f),
                                       1.421413741f), -0.284496736f), 0.254829592f);
    float y = fmaf(-p, __expf(-ax * ax), 1.0f);
    return copysignf(y, x);
}

static __device__ __forceinline__ void gload16(const unsigned short* g, unsigned short* l) {
    __builtin_amdgcn_global_load_lds(
        (const __attribute__((address_space(1))) void*)g,
        (__attribute__((address_space(3))) void*)l,
        16, 0, 0);
}

// ---------------- fp32 [K][N] -> bf16 [N][K] transpose ----------------
__global__ __launch_bounds__(256) void transpose_bf16(const float* __restrict__ in,
                                                      unsigned short* __restrict__ out,
                                                      int K, int N) {
    __shared__ float tile[32][33];
    int n0 = blockIdx.x * 32, k0 = blockIdx.y * 32;
    int tx = threadIdx.x & 31, ty = threadIdx.x >> 5;   // 32 x 8
    #pragma unroll
    for (int i = 0; i < 4; ++i)
        tile[ty + i * 8][tx] = in[(size_t)(k0 + ty + i * 8) * N + n0 + tx];
    __syncthreads();
    #pragma unroll
    for (int i = 0; i < 4; ++i)
        out[(size_t)(n0 + ty + i * 8) * K + k0 + tx] = f32_bf16(tile[tx][ty + i * 8]);
}

// ---------------- LayerNorm (fp32 in -> bf16 out) ----------------
__global__ __launch_bounds__(256) void ln_bf16(const float* __restrict__ x,
                                               const float* __restrict__ w,
                                               const float* __restrict__ bb,
                                               unsigned short* __restrict__ out) {
    int row = blockIdx.x;
    int tid = threadIdx.x;
    float4 v = ((const float4*)(x + (size_t)row * H_DIM))[tid];
    float s  = v.x + v.y + v.z + v.w;
    float s2 = v.x*v.x + v.y*v.y + v.z*v.z + v.w*v.w;
    #pragma unroll
    for (int off = 1; off < 64; off <<= 1) {
        s  += __shfl_xor(s,  off, 64);
        s2 += __shfl_xor(s2, off, 64);
    }
    __shared__ float red[8];
    int wv = tid >> 6;
    if ((tid & 63) == 0) { red[wv] = s; red[4 + wv] = s2; }
    __syncthreads();
    s  = red[0] + red[1] + red[2] + red[3];
    s2 = red[4] + red[5] + red[6] + red[7];
    float mu = s * (1.0f / H_DIM);
    float rs = rsqrtf(s2 * (1.0f / H_DIM) - mu * mu + 1e-5f);
    float4 wv4 = ((const float4*)w)[tid];
    float4 bv4 = ((const float4*)bb)[tid];
    ushort4 o;
    o.x = f32_bf16((v.x - mu) * rs * wv4.x + bv4.x);
    o.y = f32_bf16((v.y - mu) * rs * wv4.y + bv4.y);
    o.z = f32_bf16((v.z - mu) * rs * wv4.z + bv4.z);
    o.w = f32_bf16((v.w - mu) * rs * wv4.w + bv4.w);
    ((ushort4*)(out + (size_t)row * H_DIM))[tid] = o;
}

// ======== epilogue helper ========
template<int EPI>
static __device__ __forceinline__ void epi_store(f32x4 a, int row0, int col, int N,
                                                 const float* __restrict__ bias,
                                                 const float* __restrict__ resid,
                                                 float* __restrict__ outF,
                                                 unsigned short* __restrict__ outH,
                                                 unsigned short* __restrict__ outH2) {
    float bv = bias[col];
    if (EPI == 4 && col >= 2048) {
        int bb = row0 >> 11, ss = row0 & 2047;
        int hd = col - 2048;
        ushort4 u;
        u.x = f32_bf16(a[0] + bv);
        u.y = f32_bf16(a[1] + bv);
        u.z = f32_bf16(a[2] + bv);
        u.w = f32_bf16(a[3] + bv);
        *(ushort4*)&outH2[((size_t)bb * 1024 + hd) * SEQ + ss] = u;
    } else {
        #pragma unroll
        for (int j = 0; j < 4; ++j) {
            int row = row0 + j;
            size_t idx = (size_t)row * N + col;
            float c = a[j] + bv;
            if (EPI == 0) {
                outF[idx] = c;
            } else if (EPI == 1) {
                outF[idx] = resid[idx] + c;
            } else if (EPI == 2) {
                float g = 0.5f * c * (1.0f + fast_erf(c * 0.70710678118f));
                outH[idx] = f32_bf16(g);
            } else if (EPI == 3) {
                outH[idx] = f32_bf16(c);
            } else {
                // Q|K packed; Q pre-scaled into log2-softmax domain
                float c2 = (col < 1024) ? c * QSCALE : c;
                outH[(size_t)row * 2048 + col] = f32_bf16(c2);
            }
        }
    }
}

// ---------------- bf16 MFMA GEMM, 128x128 tile, BK=64, single-buffer,
//                  flat grid + XCD-chunked swizzle (round-10 proven) ----------------
template<int EPI>
__global__ __launch_bounds__(256) void gemm128(const unsigned short* __restrict__ A,
                                               const unsigned short* __restrict__ Bt,
                                               const float* __restrict__ bias,
                                               const float* __restrict__ resid,
                                               float* __restrict__ outF,
                                               unsigned short* __restrict__ outH,
                                               unsigned short* __restrict__ outH2,
                                               int gx, int N, int K) {
    __shared__ __attribute__((aligned(16))) unsigned short As[128][64];
    __shared__ __attribute__((aligned(16))) unsigned short Bs[128][64];
    int tid = threadIdx.x;
    int w = tid >> 6, l = tid & 63;
    int l15 = l & 15, lg = l >> 4;
    int wm = w & 1, wn = w >> 1;

    int qq = gridDim.x >> 3;
    int wg = (blockIdx.x & 7) * qq + (blockIdx.x >> 3);
    int bm = wg / gx, bn = wg - bm * gx;
    int m0 = bm * 128, n0 = bn * 128;

    f32x4 acc[4][4] = {};

    const unsigned short* aptr[4];
    const unsigned short* bptr[4];
    unsigned short* lA[4];
    unsigned short* lB[4];
    #pragma unroll
    for (int j = 0; j < 4; ++j) {
        int slot = (w * 4 + j) * 64 + l;          // 0..1023
        int row = slot >> 3;
        int lchunk = (slot & 7) ^ (row & 7);      // pre-swizzled source chunk
        aptr[j] = A  + (size_t)(m0 + row) * K + lchunk * 8;
        bptr[j] = Bt + (size_t)(n0 + row) * K + lchunk * 8;
        lA[j] = &As[0][0] + (w * 4 + j) * 512;
        lB[j] = &Bs[0][0] + (w * 4 + j) * 512;
    }
    int swz[2];
    swz[0] = ((0 + lg) ^ (l15 & 7)) * 8;
    swz[1] = ((4 + lg) ^ (l15 & 7)) * 8;
    const unsigned short* pA = &As[wm * 64 + l15][0];
    const unsigned short* pB = &Bs[wn * 64 + l15][0];

    for (int k0 = 0; k0 < K; k0 += 64) {
        __syncthreads();
        #pragma unroll
        for (int j = 0; j < 4; ++j) gload16(aptr[j] + k0, lA[j]);
        #pragma unroll
        for (int j = 0; j < 4; ++j) gload16(bptr[j] + k0, lB[j]);
        __syncthreads();

        #pragma unroll
        for (int ks = 0; ks < 2; ++ks) {
            short8 af[4], bf[4];
            #pragma unroll
            for (int mi = 0; mi < 4; ++mi)
                af[mi] = *(const short8*)(pA + mi * 16 * 64 + swz[ks]);
            #pragma unroll
            for (int ni = 0; ni < 4; ++ni)
                bf[ni] = *(const short8*)(pB + ni * 16 * 64 + swz[ks]);
            #pragma unroll
            for (int mi = 0; mi < 4; ++mi)
                #pragma unroll
                for (int ni = 0; ni < 4; ++ni)
                    acc[mi][ni] = __builtin_amdgcn_mfma_f32_16x16x32_bf16(af[mi], bf[ni], acc[mi][ni], 0, 0, 0);
        }
    }

    #pragma unroll
    for (int mi = 0; mi < 4; ++mi)
        #pragma unroll
        for (int ni = 0; ni < 4; ++ni)
            epi_store<EPI>(acc[mi][ni], m0 + wm * 64 + mi * 16 + lg * 4,
                           n0 + wn * 64 + ni * 16 + l15, N, bias, resid, outF, outH, outH2);
}

// ---------------- causal flash attention: swapped softmax, lean VALU path ----------------
// Scores arrive pre-scaled into log2 domain (Q pre-scaled by QSCALE in QKV epilogue).
// lsum accumulated by MFMA via a constant ones A-fragment (oext); defer-max tests
// per-lane local max only (no shfl in common path); P->bf16 via v_cvt_pk_bf16_f32.
__global__ __launch_bounds__(256) void attn_mfma(const unsigned short* __restrict__ qk,
                                                 const unsigned short* __restrict__ vT,
                                                 unsigned short* __restrict__ out) {
    int bid = blockIdx.x;
    int swz = (bid & 7) * 128 + (bid >> 3);
    int b  = swz >> 9;
    int h  = (swz >> 5) & 15;
    int qt = 31 - (swz & 31);
    int tid = threadIdx.x;
    int w = tid >> 6, l = tid & 63;
    int l15 = l & 15, lg = l >> 4;

    __shared__ __attribute__((aligned(16))) unsigned short Ks[64][72];
    __shared__ __attribute__((aligned(16))) unsigned short Vt[64][72];
    __shared__ __attribute__((aligned(16))) unsigned short Ps[4][16][72];

    int qrow = qt * 64 + w * 16 + l15;
    short8 qf[2];
    {
        const unsigned short* qp = qk + (size_t)(b * SEQ + qrow) * 2048 + h * DKV + lg * 8;
        qf[0] = *(const short8*)qp;
        qf[1] = *(const short8*)(qp + 32);
    }
    // constant ones A-fragment: row 0 (the sum row) = 1.0bf16, other rows 0
    short8 vf5;
    #pragma unroll
    for (int i = 0; i < 8; ++i) vf5[i] = (l15 == 0) ? (short)0x3F80 : (short)0;

    int srow = l >> 2;
    int scol = (l & 3) * 16;
    int krow = w * 16 + srow;
    const unsigned short* kbase = qk + (size_t)(b * SEQ + krow) * 2048 + 1024 + h * DKV + scol;
    const unsigned short* vbase = vT + ((size_t)(b * NHEAD + h) * DKV + krow) * SEQ + scol;

    short8 kr0 = *(const short8*)kbase;
    short8 kr1 = *(const short8*)(kbase + 8);
    short8 vr0 = *(const short8*)vbase;
    short8 vr1 = *(const short8*)(vbase + 8);

    float m = -1e30f;
    f32x4 oacc[4] = {};
    f32x4 oext = {};          // row 0 (lg==0, j==0) accumulates sum(P) per q=l15

    for (int kt = 0; kt <= qt; ++kt) {
        __syncthreads();
        *(short8*)&Ks[krow][scol]     = kr0;
        *(short8*)&Ks[krow][scol + 8] = kr1;
        *(short8*)&Vt[krow][scol]     = vr0;
        *(short8*)&Vt[krow][scol + 8] = vr1;
        __syncthreads();
        if (kt < qt) {
            const unsigned short* kp = kbase + (size_t)(kt + 1) * 64 * 2048;
            const unsigned short* vp = vbase + (kt + 1) * 64;
            kr0 = *(const short8*)kp;
            kr1 = *(const short8*)(kp + 8);
            vr0 = *(const short8*)vp;
            vr1 = *(const short8*)(vp + 8);
        }

        f32x4 sc[4] = {};
        __builtin_amdgcn_s_setprio(1);
        #pragma unroll
        for (int dstep = 0; dstep < 2; ++dstep) {
            #pragma unroll
            for (int st = 0; st < 4; ++st) {
                short8 kf = *(const short8*)&Ks[st * 16 + l15][dstep * 32 + lg * 8];
                sc[st] = __builtin_amdgcn_mfma_f32_16x16x32_bf16(kf, qf[dstep], sc[st], 0, 0, 0);
            }
        }
        __builtin_amdgcn_s_setprio(0);

        // scores already in log2 domain; mask + per-lane local max (fmax chains fuse to max3)
        bool diag = (kt == qt);
        int klim = w * 16 + l15;
        float pv[4][4];
        float pmax = -1e30f;
        #pragma unroll
        for (int st = 0; st < 4; ++st) {
            #pragma unroll
            for (int j = 0; j < 4; ++j) {
                float s = sc[st][j];
                if (diag && (st * 16 + lg * 4 + j > klim)) s = -1e30f;
                pv[st][j] = s;
                pmax = fmaxf(pmax, s);
            }
        }

        // defer-max: local test only (covers all 256 entries via __all over 64 lanes)
        if (!__all(pmax - m <= 8.0f)) {
            float pr = fmaxf(pmax, __shfl_xor(pmax, 16, 64));
            pr = fmaxf(pr, __shfl_xor(pr, 32, 64));
            float mn = fmaxf(m, pr);
            float scl = exp2f(m - mn);
            #pragma unroll
            for (int d = 0; d < 4; ++d)
                #pragma unroll
                for (int j = 0; j < 4; ++j)
                    oacc[d][j] *= scl;
            #pragma unroll
            for (int j = 0; j < 4; ++j) oext[j] *= scl;
            m = mn;
        }

        // P = exp2(s - m), pack to bf16 pairs via v_cvt_pk_bf16_f32
        #pragma unroll
        for (int st = 0; st < 4; ++st) {
            float p0 = exp2f(pv[st][0] - m);
            float p1 = exp2f(pv[st][1] - m);
            float p2 = exp2f(pv[st][2] - m);
            float p3 = exp2f(pv[st][3] - m);
            unsigned int ua, ub;
            asm("v_cvt_pk_bf16_f32 %0, %1, %2" : "=v"(ua) : "v"(p0), "v"(p1));
            asm("v_cvt_pk_bf16_f32 %0, %1, %2" : "=v"(ub) : "v"(p2), "v"(p3));
            uint2 u = make_uint2(ua, ub);
            *(uint2*)&Ps[w][l15][st * 16 + lg * 4] = u;
        }

        // PV + ones-row sum: O[d][q] and oext row0 = sum(P) per q
        __builtin_amdgcn_s_setprio(1);
        #pragma unroll
        for (int ks = 0; ks < 2; ++ks) {
            short8 pf = *(const short8*)&Ps[w][l15][ks * 32 + lg * 8];
            #pragma unroll
            for (int d = 0; d < 4; ++d) {
                short8 vf = *(const short8*)&Vt[d * 16 + l15][ks * 32 + lg * 8];
                oacc[d] = __builtin_amdgcn_mfma_f32_16x16x32_bf16(vf, pf, oacc[d], 0, 0, 0);
            }
            oext = __builtin_amdgcn_mfma_f32_16x16x32_bf16(vf5, pf, oext, 0, 0, 0);
        }
        __builtin_amdgcn_s_setprio(0);
    }

    // lsum sits in oext[0] of lanes 0..15 (lg==0), col q=l15 -> broadcast from lane l15
    float lsum = __shfl(oext[0], l15, 64);
    float inv = 1.0f / lsum;
    size_t ob = (size_t)(b * SEQ + qrow) * H_DIM + h * DKV;
    #pragma unroll
    for (int d = 0; d < 4; ++d) {
        ushort4 u;
        #pragma unroll
        for (int j = 0; j < 4; ++j)
            ((unsigned short*)&u)[j] = f32_bf16(oacc[d][j] * inv);
        *(ushort4*)&out[ob + d * 16 + lg * 4] = u;
    }
}

// ---------------- launch ----------------
extern "C" void kernel_launch(void* const* d_in, const int* in_sizes, int n_in,
                              void* d_out, int out_size, void* d_ws, size_t ws_size,
                              hipStream_t stream) {
    const float* x     = (const float*)d_in[0];
    const float* ln1w  = (const float*)d_in[1];
    const float* ln1b  = (const float*)d_in[2];
    const float* Wqkv  = (const float*)d_in[3];
    const float* bqkv  = (const float*)d_in[4];
    const float* Wo    = (const float*)d_in[5];
    const float* bo    = (const float*)d_in[6];
    const float* ln2w  = (const float*)d_in[7];
    const float* ln2b  = (const float*)d_in[8];
    const float* Wfc   = (const float*)d_in[9];
    const float* bfc   = (const float*)d_in[10];
    const float* Wproj = (const float*)d_in[11];
    const float* bproj = (const float*)d_in[12];
    float* out = (float*)d_out;

    char* ws = (char*)d_ws;
    size_t off = 0;
    auto take = [&](size_t bytes) {
        void* p = ws + off;
        off += (bytes + 255) & ~(size_t)255;
        return p;
    };

    unsigned short* WqT  = (unsigned short*)take((size_t)3072 * 1024 * 2);
    unsigned short* WoT  = (unsigned short*)take((size_t)1024 * 1024 * 2);
    unsigned short* WfcT = (unsigned short*)take((size_t)4096 * 1024 * 2);
    unsigned short* WpT  = (unsigned short*)take((size_t)1024 * 4096 * 2);
    unsigned short* xn1   = (unsigned short*)take((size_t)ROWS * 1024 * 2);
    unsigned short* qk_h  = (unsigned short*)take((size_t)ROWS * 2048 * 2);
    unsigned short* vT    = (unsigned short*)take((size_t)ROWS * 1024 * 2);
    unsigned short* attn  = (unsigned short*)take((size_t)ROWS * 1024 * 2);
    float*          x1    = (float*)take((size_t)ROWS * 1024 * 4);
    unsigned short* xn2   = (unsigned short*)take((size_t)ROWS * 1024 * 2);
    unsigned short* hbuf  = (unsigned short*)take((size_t)ROWS * 4096 * 2);

    // weight transposes fp32[K][N] -> bf16[N][K]
    transpose_bf16<<<dim3(3072 / 32, 1024 / 32), 256, 0, stream>>>(Wqkv,  WqT,  1024, 3072);
    transpose_bf16<<<dim3(1024 / 32, 1024 / 32), 256, 0, stream>>>(Wo,    WoT,  1024, 1024);
    transpose_bf16<<<dim3(4096 / 32, 1024 / 32), 256, 0, stream>>>(Wfc,   WfcT, 1024, 4096);
    transpose_bf16<<<dim3(1024 / 32, 4096 / 32), 256, 0, stream>>>(Wproj, WpT,  4096, 1024);

    // LN1 -> xn1 (bf16)
    ln_bf16<<<ROWS, 256, 0, stream>>>(x, ln1w, ln1b, xn1);

    // QKV: Q (pre-scaled) | K -> qk_h packed, V -> vT transposed   (grid 24x32 = 768)
    gemm128<4><<<768, 256, 0, stream>>>(xn1, WqT, bqkv, nullptr, nullptr, qk_h, vT, 24, 3072, 1024);

    // causal attention -> attn (bf16)
    attn_mfma<<<1024, 256, 0, stream>>>(qk_h, vT, attn);

    // x1 = x + attn @ Wo + bo   (grid 8x32 = 256)
    gemm128<1><<<256, 256, 0, stream>>>(attn, WoT, bo, x, x1, nullptr, nullptr, 8, 1024, 1024);

    // LN2 -> xn2 (bf16)
    ln_bf16<<<ROWS, 256, 0, stream>>>(x1, ln2w, ln2b, xn2);

    // h = gelu(xn2 @ Wfc + bfc)   (grid 32x32 = 1024)
    gemm128<2><<<1024, 256, 0, stream>>>(xn2, WfcT, bfc, nullptr, nullptr, hbuf, nullptr, 32, 4096, 1024);

    // out = x1 + h @ Wproj + bproj   (grid 8x32 = 256)
    gemm128<1><<<256, 256, 0, stream>>>(hbuf, WpT, bproj, x1, out, nullptr, nullptr, 8, 1024, 4096);
}

// Round 13
// 258.717 us; speedup vs baseline: 1.1497x; 1.0755x over previous
//
#include <hip/hip_runtime.h>
#include <hip/hip_bf16.h>
#include <math.h>

#define H_DIM 1024
#define SEQ   2048
#define BATCH 2
#define NHEAD 16
#define DKV   64
#define ROWS  (BATCH*SEQ)   // 4096
#define QSCALE 0.18033688f  // 0.125 * log2(e): scores land in log2 domain

typedef __attribute__((ext_vector_type(8))) short short8;
typedef __attribute__((ext_vector_type(4))) float f32x4;

static __device__ __forceinline__ unsigned short f32_bf16(float f) {
    unsigned int u = __builtin_bit_cast(unsigned int, f);
    u += 0x7FFF + ((u >> 16) & 1);          // RNE
    return (unsigned short)(u >> 16);
}

// A&S 7.1.26 rational-poly erf, |err| < 1.5e-7
static __device__ __forceinline__ float fast_erf(float x) {
    float ax = fabsf(x);
    float t = 1.0f / fmaf(0.3275911f, ax, 1.0f);
    float p = t * fmaf(t, fmaf(t, fmaf(t, fmaf(t, 1.061405429f, -1.453152027f),
                                       1.421413741f), -0.284496736f), 0.254829592f);
    float y = fmaf(-p, __expf(-ax * ax), 1.0f);
    return copysignf(y, x);
}

static __device__ __forceinline__ void gload16(const unsigned short* g, unsigned short* l) {
    __builtin_amdgcn_global_load_lds(
        (const __attribute__((address_space(1))) void*)g,
        (__attribute__((address_space(3))) void*)l,
        16, 0, 0);
}

// ---------------- fp32 [K][N] -> bf16 [N][K] transpose ----------------
__global__ __launch_bounds__(256) void transpose_bf16(const float* __restrict__ in,
                                                      unsigned short* __restrict__ out,
                                                      int K, int N) {
    __shared__ float tile[32][33];
    int n0 = blockIdx.x * 32, k0 = blockIdx.y * 32;
    int tx = threadIdx.x & 31, ty = threadIdx.x >> 5;   // 32 x 8
    #pragma unroll
    for (int i = 0; i < 4; ++i)
        tile[ty + i * 8][tx] = in[(size_t)(k0 + ty + i * 8) * N + n0 + tx];
    __syncthreads();
    #pragma unroll
    for (int i = 0; i < 4; ++i)
        out[(size_t)(n0 + ty + i * 8) * K + k0 + tx] = f32_bf16(tile[tx][ty + i * 8]);
}

// ---------------- LayerNorm (fp32 in -> bf16 out) ----------------
__global__ __launch_bounds__(256) void ln_bf16(const float* __restrict__ x,
                                               const float* __restrict__ w,
                                               const float* __restrict__ bb,
                                               unsigned short* __restrict__ out) {
    int row = blockIdx.x;
    int tid = threadIdx.x;
    float4 v = ((const float4*)(x + (size_t)row * H_DIM))[tid];
    float s  = v.x + v.y + v.z + v.w;
    float s2 = v.x*v.x + v.y*v.y + v.z*v.z + v.w*v.w;
    #pragma unroll
    for (int off = 1; off < 64; off <<= 1) {
        s  += __shfl_xor(s,  off, 64);
        s2 += __shfl_xor(s2, off, 64);
    }
    __shared__ float red[8];
    int wv = tid >> 6;
    if ((tid & 63) == 0) { red[wv] = s; red[4 + wv] = s2; }
    __syncthreads();
    s  = red[0] + red[1] + red[2] + red[3];
    s2 = red[4] + red[5] + red[6] + red[7];
    float mu = s * (1.0f / H_DIM);
    float rs = rsqrtf(s2 * (1.0f / H_DIM) - mu * mu + 1e-5f);
    float4 wv4 = ((const float4*)w)[tid];
    float4 bv4 = ((const float4*)bb)[tid];
    ushort4 o;
    o.x = f32_bf16((v.x - mu) * rs * wv4.x + bv4.x);
    o.y = f32_bf16((v.y - mu) * rs * wv4.y + bv4.y);
    o.z = f32_bf16((v.z - mu) * rs * wv4.z + bv4.z);
    o.w = f32_bf16((v.w - mu) * rs * wv4.w + bv4.w);
    ((ushort4*)(out + (size_t)row * H_DIM))[tid] = o;
}

// ======== epilogue helper ========
template<int EPI>
static __device__ __forceinline__ void epi_store(f32x4 a, int row0, int col, int N,
                                                 const float* __restrict__ bias,
                                                 const float* __restrict__ resid,
                                                 float* __restrict__ outF,
                                                 unsigned short* __restrict__ outH,
                                                 unsigned short* __restrict__ outH2) {
    float bv = bias[col];
    if (EPI == 4 && col >= 2048) {
        int bb = row0 >> 11, ss = row0 & 2047;
        int hd = col - 2048;
        ushort4 u;
        u.x = f32_bf16(a[0] + bv);
        u.y = f32_bf16(a[1] + bv);
        u.z = f32_bf16(a[2] + bv);
        u.w = f32_bf16(a[3] + bv);
        *(ushort4*)&outH2[((size_t)bb * 1024 + hd) * SEQ + ss] = u;
    } else {
        #pragma unroll
        for (int j = 0; j < 4; ++j) {
            int row = row0 + j;
            size_t idx = (size_t)row * N + col;
            float c = a[j] + bv;
            if (EPI == 0) {
                outF[idx] = c;
            } else if (EPI == 1) {
                outF[idx] = resid[idx] + c;
            } else if (EPI == 2) {
                float g = 0.5f * c * (1.0f + fast_erf(c * 0.70710678118f));
                outH[idx] = f32_bf16(g);
            } else if (EPI == 3) {
                outH[idx] = f32_bf16(c);
            } else {
                // Q|K packed; Q pre-scaled into log2-softmax domain
                float c2 = (col < 1024) ? c * QSCALE : c;
                outH[(size_t)row * 2048 + col] = f32_bf16(c2);
            }
        }
    }
}

// ---------------- bf16 MFMA GEMM, 128 x (NI*32) tile, BK=64, single-buffer,
//                  flat grid + XCD-chunked swizzle (round-10/12 proven core) ----------------
// NI=4: 128x128 (QKV/FC). NI=2: 128x64 (Wo/Proj -> grid 512 = 2 blocks/CU overlap).
template<int EPI, int NI>
__global__ __launch_bounds__(256) void gemmT(const unsigned short* __restrict__ A,
                                             const unsigned short* __restrict__ Bt,
                                             const float* __restrict__ bias,
                                             const float* __restrict__ resid,
                                             float* __restrict__ outF,
                                             unsigned short* __restrict__ outH,
                                             unsigned short* __restrict__ outH2,
                                             int gx, int N, int K) {
    constexpr int BN = NI * 32;
    __shared__ __attribute__((aligned(16))) unsigned short As[128][64];
    __shared__ __attribute__((aligned(16))) unsigned short Bs[BN][64];
    int tid = threadIdx.x;
    int w = tid >> 6, l = tid & 63;
    int l15 = l & 15, lg = l >> 4;
    int wm = w & 1, wn = w >> 1;

    int qq = gridDim.x >> 3;
    int wg = (blockIdx.x & 7) * qq + (blockIdx.x >> 3);
    int bm = wg / gx, bn = wg - bm * gx;
    int m0 = bm * 128, n0 = bn * BN;

    f32x4 acc[4][NI] = {};

    const unsigned short* aptr[4];
    unsigned short* lA[4];
    #pragma unroll
    for (int j = 0; j < 4; ++j) {
        int slot = (w * 4 + j) * 64 + l;          // 0..1023
        int row = slot >> 3;
        int lchunk = (slot & 7) ^ (row & 7);      // pre-swizzled source chunk
        aptr[j] = A + (size_t)(m0 + row) * K + lchunk * 8;
        lA[j] = &As[0][0] + (w * 4 + j) * 512;
    }
    const unsigned short* bptr[NI];
    unsigned short* lB[NI];
    #pragma unroll
    for (int j = 0; j < NI; ++j) {
        int slot = (w * NI + j) * 64 + l;         // 0..BN*8-1
        int row = slot >> 3;
        int lchunk = (slot & 7) ^ (row & 7);
        bptr[j] = Bt + (size_t)(n0 + row) * K + lchunk * 8;
        lB[j] = &Bs[0][0] + (w * NI + j) * 512;
    }
    int swz[2];
    swz[0] = ((0 + lg) ^ (l15 & 7)) * 8;
    swz[1] = ((4 + lg) ^ (l15 & 7)) * 8;
    const unsigned short* pA = &As[wm * 64 + l15][0];
    const unsigned short* pB = &Bs[wn * (NI * 16) + l15][0];

    for (int k0 = 0; k0 < K; k0 += 64) {
        __syncthreads();
        #pragma unroll
        for (int j = 0; j < 4; ++j) gload16(aptr[j] + k0, lA[j]);
        #pragma unroll
        for (int j = 0; j < NI; ++j) gload16(bptr[j] + k0, lB[j]);
        __syncthreads();

        #pragma unroll
        for (int ks = 0; ks < 2; ++ks) {
            short8 af[4], bf[NI];
            #pragma unroll
            for (int mi = 0; mi < 4; ++mi)
                af[mi] = *(const short8*)(pA + mi * 16 * 64 + swz[ks]);
            #pragma unroll
            for (int ni = 0; ni < NI; ++ni)
                bf[ni] = *(const short8*)(pB + ni * 16 * 64 + swz[ks]);
            #pragma unroll
            for (int mi = 0; mi < 4; ++mi)
                #pragma unroll
                for (int ni = 0; ni < NI; ++ni)
                    acc[mi][ni] = __builtin_amdgcn_mfma_f32_16x16x32_bf16(af[mi], bf[ni], acc[mi][ni], 0, 0, 0);
        }
    }

    #pragma unroll
    for (int mi = 0; mi < 4; ++mi)
        #pragma unroll
        for (int ni = 0; ni < NI; ++ni)
            epi_store<EPI>(acc[mi][ni], m0 + wm * 64 + mi * 16 + lg * 4,
                           n0 + wn * (NI * 16) + ni * 16 + l15, N, bias, resid, outF, outH, outH2);
}

// ---------------- causal flash attention: QBLK=128, 8 waves, swapped softmax ----------------
// Grid 512 = B*NH*(SEQ/128); each wave owns 16 q-rows; K/V staged once per 128 q-rows
// (halves staging traffic + barrier overhead vs QBLK=64). Waves 0-3 eat one fully-masked
// tail tile (P=0 via mask). All softmax tricks from round 12 retained.
__global__ __launch_bounds__(512) void attn_mfma(const unsigned short* __restrict__ qk,
                                                 const unsigned short* __restrict__ vT,
                                                 unsigned short* __restrict__ out) {
    int bid = blockIdx.x;
    int swz = (bid & 7) * 64 + (bid >> 3);    // 512 % 8 == 0 -> bijective
    int b  = swz >> 8;
    int h  = (swz >> 4) & 15;
    int qt = 15 - (swz & 15);                 // long blocks first
    int tid = threadIdx.x;
    int w = tid >> 6, l = tid & 63;
    int l15 = l & 15, lg = l >> 4;

    __shared__ __attribute__((aligned(16))) unsigned short Ks[64][72];
    __shared__ __attribute__((aligned(16))) unsigned short Vt[64][72];
    __shared__ __attribute__((aligned(16))) unsigned short Ps[8][16][72];

    int qrow = qt * 128 + w * 16 + l15;       // this lane's q row
    short8 qf[2];
    {
        const unsigned short* qp = qk + (size_t)(b * SEQ + qrow) * 2048 + h * DKV + lg * 8;
        qf[0] = *(const short8*)qp;
        qf[1] = *(const short8*)(qp + 32);
    }
    short8 vf5;
    #pragma unroll
    for (int i = 0; i < 8; ++i) vf5[i] = (l15 == 0) ? (short)0x3F80 : (short)0;

    // staging: 512 threads, one short8 each for K and V (8KB tiles)
    int srow = tid >> 3;                      // 0..63
    int scol = (tid & 7) * 8;
    const unsigned short* kbase = qk + (size_t)(b * SEQ + srow) * 2048 + 1024 + h * DKV + scol;
    const unsigned short* vbase = vT + ((size_t)(b * NHEAD + h) * DKV + srow) * SEQ + scol;

    short8 kr = *(const short8*)kbase;
    short8 vr = *(const short8*)vbase;

    float m = -1e30f;
    f32x4 oacc[4] = {};
    f32x4 oext = {};

    int nt = 2 * qt + 2;
    for (int kt = 0; kt < nt; ++kt) {
        __syncthreads();
        *(short8*)&Ks[srow][scol] = kr;
        *(short8*)&Vt[srow][scol] = vr;
        __syncthreads();
        if (kt + 1 < nt) {
            kr = *(const short8*)(kbase + (size_t)(kt + 1) * 64 * 2048);
            vr = *(const short8*)(vbase + (kt + 1) * 64);
        }

        f32x4 sc[4] = {};
        __builtin_amdgcn_s_setprio(1);
        #pragma unroll
        for (int dstep = 0; dstep < 2; ++dstep) {
            #pragma unroll
            for (int st = 0; st < 4; ++st) {
                short8 kf = *(const short8*)&Ks[st * 16 + l15][dstep * 32 + lg * 8];
                sc[st] = __builtin_amdgcn_mfma_f32_16x16x32_bf16(kf, qf[dstep], sc[st], 0, 0, 0);
            }
        }
        __builtin_amdgcn_s_setprio(0);

        // mask vs this lane's q row (handles past/diag/future uniformly)
        int klim = qrow - kt * 64;            // within-tile causal threshold
        float pv[4][4];
        float pmax = -1e30f;
        #pragma unroll
        for (int st = 0; st < 4; ++st) {
            #pragma unroll
            for (int j = 0; j < 4; ++j) {
                float s = sc[st][j];
                if (st * 16 + lg * 4 + j > klim) s = -1e30f;
                pv[st][j] = s;
                pmax = fmaxf(pmax, s);
            }
        }

        if (!__all(pmax - m <= 8.0f)) {
            float pr = fmaxf(pmax, __shfl_xor(pmax, 16, 64));
            pr = fmaxf(pr, __shfl_xor(pr, 32, 64));
            float mn = fmaxf(m, pr);
            float scl = exp2f(m - mn);
            #pragma unroll
            for (int d = 0; d < 4; ++d)
                #pragma unroll
                for (int j = 0; j < 4; ++j)
                    oacc[d][j] *= scl;
            #pragma unroll
            for (int j = 0; j < 4; ++j) oext[j] *= scl;
            m = mn;
        }

        #pragma unroll
        for (int st = 0; st < 4; ++st) {
            float p0 = exp2f(pv[st][0] - m);
            float p1 = exp2f(pv[st][1] - m);
            float p2 = exp2f(pv[st][2] - m);
            float p3 = exp2f(pv[st][3] - m);
            unsigned int ua, ub;
            asm("v_cvt_pk_bf16_f32 %0, %1, %2" : "=v"(ua) : "v"(p0), "v"(p1));
            asm("v_cvt_pk_bf16_f32 %0, %1, %2" : "=v"(ub) : "v"(p2), "v"(p3));
            uint2 u = make_uint2(ua, ub);
            *(uint2*)&Ps[w][l15][st * 16 + lg * 4] = u;
        }

        __builtin_amdgcn_s_setprio(1);
        #pragma unroll
        for (int ks = 0; ks < 2; ++ks) {
            short8 pf = *(const short8*)&Ps[w][l15][ks * 32 + lg * 8];
            #pragma unroll
            for (int d = 0; d < 4; ++d) {
                short8 vf = *(const short8*)&Vt[d * 16 + l15][ks * 32 + lg * 8];
                oacc[d] = __builtin_amdgcn_mfma_f32_16x16x32_bf16(vf, pf, oacc[d], 0, 0, 0);
            }
            oext = __builtin_amdgcn_mfma_f32_16x16x32_bf16(vf5, pf, oext, 0, 0, 0);
        }
        __builtin_amdgcn_s_setprio(0);
    }

    float lsum = __shfl(oext[0], l15, 64);
    float inv = 1.0f / lsum;
    size_t ob = (size_t)(b * SEQ + qrow) * H_DIM + h * DKV;
    #pragma unroll
    for (int d = 0; d < 4; ++d) {
        ushort4 u;
        #pragma unroll
        for (int j = 0; j < 4; ++j)
            ((unsigned short*)&u)[j] = f32_bf16(oacc[d][j] * inv);
        *(ushort4*)&out[ob + d * 16 + lg * 4] = u;
    }
}

// ---------------- launch ----------------
extern "C" void kernel_launch(void* const* d_in, const int* in_sizes, int n_in,
                              void* d_out, int out_size, void* d_ws, size_t ws_size,
                              hipStream_t stream) {
    const float* x     = (const float*)d_in[0];
    const float* ln1w  = (const float*)d_in[1];
    const float* ln1b  = (const float*)d_in[2];
    const float* Wqkv  = (const float*)d_in[3];
    const float* bqkv  = (const float*)d_in[4];
    const float* Wo    = (const float*)d_in[5];
    const float* bo    = (const float*)d_in[6];
    const float* ln2w  = (const float*)d_in[7];
    const float* ln2b  = (const float*)d_in[8];
    const float* Wfc   = (const float*)d_in[9];
    const float* bfc   = (const float*)d_in[10];
    const float* Wproj = (const float*)d_in[11];
    const float* bproj = (const float*)d_in[12];
    float* out = (float*)d_out;

    char* ws = (char*)d_ws;
    size_t off = 0;
    auto take = [&](size_t bytes) {
        void* p = ws + off;
        off += (bytes + 255) & ~(size_t)255;
        return p;
    };

    unsigned short* WqT  = (unsigned short*)take((size_t)3072 * 1024 * 2);
    unsigned short* WoT  = (unsigned short*)take((size_t)1024 * 1024 * 2);
    unsigned short* WfcT = (unsigned short*)take((size_t)4096 * 1024 * 2);
    unsigned short* WpT  = (unsigned short*)take((size_t)1024 * 4096 * 2);
    unsigned short* xn1   = (unsigned short*)take((size_t)ROWS * 1024 * 2);
    unsigned short* qk_h  = (unsigned short*)take((size_t)ROWS * 2048 * 2);
    unsigned short* vT    = (unsigned short*)take((size_t)ROWS * 1024 * 2);
    unsigned short* attn  = (unsigned short*)take((size_t)ROWS * 1024 * 2);
    float*          x1    = (float*)take((size_t)ROWS * 1024 * 4);
    unsigned short* xn2   = (unsigned short*)take((size_t)ROWS * 1024 * 2);
    unsigned short* hbuf  = (unsigned short*)take((size_t)ROWS * 4096 * 2);

    // weight transposes fp32[K][N] -> bf16[N][K]
    transpose_bf16<<<dim3(3072 / 32, 1024 / 32), 256, 0, stream>>>(Wqkv,  WqT,  1024, 3072);
    transpose_bf16<<<dim3(1024 / 32, 1024 / 32), 256, 0, stream>>>(Wo,    WoT,  1024, 1024);
    transpose_bf16<<<dim3(4096 / 32, 1024 / 32), 256, 0, stream>>>(Wfc,   WfcT, 1024, 4096);
    transpose_bf16<<<dim3(1024 / 32, 4096 / 32), 256, 0, stream>>>(Wproj, WpT,  4096, 1024);

    // LN1 -> xn1 (bf16)
    ln_bf16<<<ROWS, 256, 0, stream>>>(x, ln1w, ln1b, xn1);

    // QKV: Q (pre-scaled) | K -> qk_h packed, V -> vT transposed   (grid 24x32 = 768)
    gemmT<4, 4><<<768, 256, 0, stream>>>(xn1, WqT, bqkv, nullptr, nullptr, qk_h, vT, 24, 3072, 1024);

    // causal attention -> attn (bf16), QBLK=128, grid 512
    attn_mfma<<<512, 512, 0, stream>>>(qk_h, vT, attn);

    // x1 = x + attn @ Wo + bo   (128x64 tile, grid 16x32 = 512)
    gemmT<1, 2><<<512, 256, 0, stream>>>(attn, WoT, bo, x, x1, nullptr, nullptr, 16, 1024, 1024);

    // LN2 -> xn2 (bf16)
    ln_bf16<<<ROWS, 256, 0, stream>>>(x1, ln2w, ln2b, xn2);

    // h = gelu(xn2 @ Wfc + bfc)   (grid 32x32 = 1024)
    gemmT<2, 4><<<1024, 256, 0, stream>>>(xn2, WfcT, bfc, nullptr, nullptr, hbuf, nullptr, 32, 4096, 1024);

    // out = x1 + h @ Wproj + bproj   (128x64 tile, grid 16x32 = 512)
    gemmT<1, 2><<<512, 256, 0, stream>>>(hbuf, WpT, bproj, x1, out, nullptr, nullptr, 16, 1024, 4096);
}

// Round 14
// 248.821 us; speedup vs baseline: 1.1954x; 1.0398x over previous
//
#include <hip/hip_runtime.h>
#include <hip/hip_bf16.h>
#include <math.h>

#define H_DIM 1024
#define SEQ   2048
#define BATCH 2
#define NHEAD 16
#define DKV   64
#define ROWS  (BATCH*SEQ)   // 4096
#define QSCALE 0.18033688f  // 0.125 * log2(e): scores land in log2 domain

typedef __attribute__((ext_vector_type(8))) short short8;
typedef __attribute__((ext_vector_type(4))) float f32x4;

static __device__ __forceinline__ unsigned short f32_bf16(float f) {
    unsigned int u = __builtin_bit_cast(unsigned int, f);
    u += 0x7FFF + ((u >> 16) & 1);          // RNE
    return (unsigned short)(u >> 16);
}

// A&S 7.1.26 rational-poly erf, |err| < 1.5e-7
static __device__ __forceinline__ float fast_erf(float x) {
    float ax = fabsf(x);
    float t = 1.0f / fmaf(0.3275911f, ax, 1.0f);
    float p = t * fmaf(t, fmaf(t, fmaf(t, fmaf(t, 1.061405429f, -1.453152027f),
                                       1.421413741f), -0.284496736f), 0.254829592f);
    float y = fmaf(-p, __expf(-ax * ax), 1.0f);
    return copysignf(y, x);
}

static __device__ __forceinline__ void gload16(const unsigned short* g, unsigned short* l) {
    __builtin_amdgcn_global_load_lds(
        (const __attribute__((address_space(1))) void*)g,
        (__attribute__((address_space(3))) void*)l,
        16, 0, 0);
}

// ---------------- fp32 [K][N] -> bf16 [N][K] transpose ----------------
__global__ __launch_bounds__(256) void transpose_bf16(const float* __restrict__ in,
                                                      unsigned short* __restrict__ out,
                                                      int K, int N) {
    __shared__ float tile[32][33];
    int n0 = blockIdx.x * 32, k0 = blockIdx.y * 32;
    int tx = threadIdx.x & 31, ty = threadIdx.x >> 5;   // 32 x 8
    #pragma unroll
    for (int i = 0; i < 4; ++i)
        tile[ty + i * 8][tx] = in[(size_t)(k0 + ty + i * 8) * N + n0 + tx];
    __syncthreads();
    #pragma unroll
    for (int i = 0; i < 4; ++i)
        out[(size_t)(n0 + ty + i * 8) * K + k0 + tx] = f32_bf16(tile[tx][ty + i * 8]);
}

// ---------------- LayerNorm (fp32 in -> bf16 out) ----------------
__global__ __launch_bounds__(256) void ln_bf16(const float* __restrict__ x,
                                               const float* __restrict__ w,
                                               const float* __restrict__ bb,
                                               unsigned short* __restrict__ out) {
    int row = blockIdx.x;
    int tid = threadIdx.x;
    float4 v = ((const float4*)(x + (size_t)row * H_DIM))[tid];
    float s  = v.x + v.y + v.z + v.w;
    float s2 = v.x*v.x + v.y*v.y + v.z*v.z + v.w*v.w;
    #pragma unroll
    for (int off = 1; off < 64; off <<= 1) {
        s  += __shfl_xor(s,  off, 64);
        s2 += __shfl_xor(s2, off, 64);
    }
    __shared__ float red[8];
    int wv = tid >> 6;
    if ((tid & 63) == 0) { red[wv] = s; red[4 + wv] = s2; }
    __syncthreads();
    s  = red[0] + red[1] + red[2] + red[3];
    s2 = red[4] + red[5] + red[6] + red[7];
    float mu = s * (1.0f / H_DIM);
    float rs = rsqrtf(s2 * (1.0f / H_DIM) - mu * mu + 1e-5f);
    float4 wv4 = ((const float4*)w)[tid];
    float4 bv4 = ((const float4*)bb)[tid];
    ushort4 o;
    o.x = f32_bf16((v.x - mu) * rs * wv4.x + bv4.x);
    o.y = f32_bf16((v.y - mu) * rs * wv4.y + bv4.y);
    o.z = f32_bf16((v.z - mu) * rs * wv4.z + bv4.z);
    o.w = f32_bf16((v.w - mu) * rs * wv4.w + bv4.w);
    ((ushort4*)(out + (size_t)row * H_DIM))[tid] = o;
}

// ======== epilogue helper ========
template<int EPI>
static __device__ __forceinline__ void epi_store(f32x4 a, int row0, int col, int N,
                                                 const float* __restrict__ bias,
                                                 const float* __restrict__ resid,
                                                 float* __restrict__ outF,
                                                 unsigned short* __restrict__ outH,
                                                 unsigned short* __restrict__ outH2) {
    float bv = bias[col];
    if (EPI == 4 && col >= 2048) {
        int bb = row0 >> 11, ss = row0 & 2047;
        int hd = col - 2048;
        ushort4 u;
        u.x = f32_bf16(a[0] + bv);
        u.y = f32_bf16(a[1] + bv);
        u.z = f32_bf16(a[2] + bv);
        u.w = f32_bf16(a[3] + bv);
        *(ushort4*)&outH2[((size_t)bb * 1024 + hd) * SEQ + ss] = u;
    } else {
        #pragma unroll
        for (int j = 0; j < 4; ++j) {
            int row = row0 + j;
            size_t idx = (size_t)row * N + col;
            float c = a[j] + bv;
            if (EPI == 0) {
                outF[idx] = c;
            } else if (EPI == 1) {
                outF[idx] = resid[idx] + c;
            } else if (EPI == 2) {
                float g = 0.5f * c * (1.0f + fast_erf(c * 0.70710678118f));
                outH[idx] = f32_bf16(g);
            } else if (EPI == 3) {
                outH[idx] = f32_bf16(c);
            } else {
                // Q|K packed; Q pre-scaled into log2-softmax domain
                float c2 = (col < 1024) ? c * QSCALE : c;
                outH[(size_t)row * 2048 + col] = f32_bf16(c2);
            }
        }
    }
}

// ---------------- bf16 MFMA GEMM, 128 x (NI*32) tile, BK=64, single-buffer,
//                  8 waves (512 thr), wave-tile 64 x (NI*8): low regs -> high occupancy ----
// NI=4: 128x128 (QKV/FC), wave 64x32, acc[4][2]. NI=2: 128x64 (Wo/Proj), wave 64x16, acc[4][1].
// Proven chunk-XOR LDS swizzle + XCD-chunked flat grid retained.
template<int EPI, int NI>
__global__ __launch_bounds__(512) void gemmT(const unsigned short* __restrict__ A,
                                             const unsigned short* __restrict__ Bt,
                                             const float* __restrict__ bias,
                                             const float* __restrict__ resid,
                                             float* __restrict__ outF,
                                             unsigned short* __restrict__ outH,
                                             unsigned short* __restrict__ outH2,
                                             int gx, int N, int K) {
    constexpr int BN = NI * 32;
    constexpr int WN = BN / 4;        // wave col-span: 32 or 16
    constexpr int NT = WN / 16;       // ni tiles per wave: 2 or 1
    __shared__ __attribute__((aligned(16))) unsigned short As[128][64];
    __shared__ __attribute__((aligned(16))) unsigned short Bs[BN][64];
    int tid = threadIdx.x;
    int w = tid >> 6, l = tid & 63;   // 8 waves
    int l15 = l & 15, lg = l >> 4;
    int wm = w & 1, wn = w >> 1;      // 2 (M) x 4 (N)

    int qq = gridDim.x >> 3;
    int wg = (blockIdx.x & 7) * qq + (blockIdx.x >> 3);
    int bm = wg / gx, bn = wg - bm * gx;
    int m0 = bm * 128, n0 = bn * BN;

    f32x4 acc[4][NT] = {};

    // A staging: 1024 chunks (16KB), 2 gload16/thread
    const unsigned short* aptr[2];
    unsigned short* lA[2];
    #pragma unroll
    for (int j = 0; j < 2; ++j) {
        int slot = j * 512 + tid;                 // 0..1023
        int row = slot >> 3;
        int lchunk = (slot & 7) ^ (row & 7);      // pre-swizzled source chunk
        aptr[j] = A + (size_t)(m0 + row) * K + lchunk * 8;
        lA[j] = &As[0][0] + (size_t)slot * 8 - l * 8;   // wave-uniform base (+lane*16B HW)
    }
    // B staging: BN*8 chunks, NI/2 gload16/thread
    const unsigned short* bptr[NI / 2];
    unsigned short* lB[NI / 2];
    #pragma unroll
    for (int j = 0; j < NI / 2; ++j) {
        int slot = j * 512 + tid;
        int row = slot >> 3;
        int lchunk = (slot & 7) ^ (row & 7);
        bptr[j] = Bt + (size_t)(n0 + row) * K + lchunk * 8;
        lB[j] = &Bs[0][0] + (size_t)slot * 8 - l * 8;
    }
    int swz[2];
    swz[0] = ((0 + lg) ^ (l15 & 7)) * 8;
    swz[1] = ((4 + lg) ^ (l15 & 7)) * 8;
    const unsigned short* pA = &As[wm * 64 + l15][0];
    const unsigned short* pB = &Bs[wn * WN + l15][0];

    for (int k0 = 0; k0 < K; k0 += 64) {
        __syncthreads();
        #pragma unroll
        for (int j = 0; j < 2; ++j) gload16(aptr[j] + k0, lA[j]);
        #pragma unroll
        for (int j = 0; j < NI / 2; ++j) gload16(bptr[j] + k0, lB[j]);
        __syncthreads();

        #pragma unroll
        for (int ks = 0; ks < 2; ++ks) {
            short8 af[4], bf[NT];
            #pragma unroll
            for (int mi = 0; mi < 4; ++mi)
                af[mi] = *(const short8*)(pA + mi * 16 * 64 + swz[ks]);
            #pragma unroll
            for (int ni = 0; ni < NT; ++ni)
                bf[ni] = *(const short8*)(pB + ni * 16 * 64 + swz[ks]);
            #pragma unroll
            for (int mi = 0; mi < 4; ++mi)
                #pragma unroll
                for (int ni = 0; ni < NT; ++ni)
                    acc[mi][ni] = __builtin_amdgcn_mfma_f32_16x16x32_bf16(af[mi], bf[ni], acc[mi][ni], 0, 0, 0);
        }
    }

    #pragma unroll
    for (int mi = 0; mi < 4; ++mi)
        #pragma unroll
        for (int ni = 0; ni < NT; ++ni)
            epi_store<EPI>(acc[mi][ni], m0 + wm * 64 + mi * 16 + lg * 4,
                           n0 + wn * WN + ni * 16 + l15, N, bias, resid, outF, outH, outH2);
}

// ---------------- causal flash attention: QBLK=128, 8 waves, swapped softmax ----------------
__global__ __launch_bounds__(512) void attn_mfma(const unsigned short* __restrict__ qk,
                                                 const unsigned short* __restrict__ vT,
                                                 unsigned short* __restrict__ out) {
    int bid = blockIdx.x;
    int swz = (bid & 7) * 64 + (bid >> 3);    // 512 % 8 == 0 -> bijective
    int b  = swz >> 8;
    int h  = (swz >> 4) & 15;
    int qt = 15 - (swz & 15);                 // long blocks first
    int tid = threadIdx.x;
    int w = tid >> 6, l = tid & 63;
    int l15 = l & 15, lg = l >> 4;

    __shared__ __attribute__((aligned(16))) unsigned short Ks[64][72];
    __shared__ __attribute__((aligned(16))) unsigned short Vt[64][72];
    __shared__ __attribute__((aligned(16))) unsigned short Ps[8][16][72];

    int qrow = qt * 128 + w * 16 + l15;       // this lane's q row
    short8 qf[2];
    {
        const unsigned short* qp = qk + (size_t)(b * SEQ + qrow) * 2048 + h * DKV + lg * 8;
        qf[0] = *(const short8*)qp;
        qf[1] = *(const short8*)(qp + 32);
    }
    short8 vf5;
    #pragma unroll
    for (int i = 0; i < 8; ++i) vf5[i] = (l15 == 0) ? (short)0x3F80 : (short)0;

    int srow = tid >> 3;                      // 0..63
    int scol = (tid & 7) * 8;
    const unsigned short* kbase = qk + (size_t)(b * SEQ + srow) * 2048 + 1024 + h * DKV + scol;
    const unsigned short* vbase = vT + ((size_t)(b * NHEAD + h) * DKV + srow) * SEQ + scol;

    short8 kr = *(const short8*)kbase;
    short8 vr = *(const short8*)vbase;

    float m = -1e30f;
    f32x4 oacc[4] = {};
    f32x4 oext = {};

    int nt = 2 * qt + 2;
    for (int kt = 0; kt < nt; ++kt) {
        __syncthreads();
        *(short8*)&Ks[srow][scol] = kr;
        *(short8*)&Vt[srow][scol] = vr;
        __syncthreads();
        if (kt + 1 < nt) {
            kr = *(const short8*)(kbase + (size_t)(kt + 1) * 64 * 2048);
            vr = *(const short8*)(vbase + (kt + 1) * 64);
        }

        f32x4 sc[4] = {};
        __builtin_amdgcn_s_setprio(1);
        #pragma unroll
        for (int dstep = 0; dstep < 2; ++dstep) {
            #pragma unroll
            for (int st = 0; st < 4; ++st) {
                short8 kf = *(const short8*)&Ks[st * 16 + l15][dstep * 32 + lg * 8];
                sc[st] = __builtin_amdgcn_mfma_f32_16x16x32_bf16(kf, qf[dstep], sc[st], 0, 0, 0);
            }
        }
        __builtin_amdgcn_s_setprio(0);

        int klim = qrow - kt * 64;            // within-tile causal threshold
        float pv[4][4];
        float pmax = -1e30f;
        #pragma unroll
        for (int st = 0; st < 4; ++st) {
            #pragma unroll
            for (int j = 0; j < 4; ++j) {
                float s = sc[st][j];
                if (st * 16 + lg * 4 + j > klim) s = -1e30f;
                pv[st][j] = s;
                pmax = fmaxf(pmax, s);
            }
        }

        if (!__all(pmax - m <= 8.0f)) {
            float pr = fmaxf(pmax, __shfl_xor(pmax, 16, 64));
            pr = fmaxf(pr, __shfl_xor(pr, 32, 64));
            float mn = fmaxf(m, pr);
            float scl = exp2f(m - mn);
            #pragma unroll
            for (int d = 0; d < 4; ++d)
                #pragma unroll
                for (int j = 0; j < 4; ++j)
                    oacc[d][j] *= scl;
            #pragma unroll
            for (int j = 0; j < 4; ++j) oext[j] *= scl;
            m = mn;
        }

        #pragma unroll
        for (int st = 0; st < 4; ++st) {
            float p0 = exp2f(pv[st][0] - m);
            float p1 = exp2f(pv[st][1] - m);
            float p2 = exp2f(pv[st][2] - m);
            float p3 = exp2f(pv[st][3] - m);
            unsigned int ua, ub;
            asm("v_cvt_pk_bf16_f32 %0, %1, %2" : "=v"(ua) : "v"(p0), "v"(p1));
            asm("v_cvt_pk_bf16_f32 %0, %1, %2" : "=v"(ub) : "v"(p2), "v"(p3));
            uint2 u = make_uint2(ua, ub);
            *(uint2*)&Ps[w][l15][st * 16 + lg * 4] = u;
        }

        __builtin_amdgcn_s_setprio(1);
        #pragma unroll
        for (int ks = 0; ks < 2; ++ks) {
            short8 pf = *(const short8*)&Ps[w][l15][ks * 32 + lg * 8];
            #pragma unroll
            for (int d = 0; d < 4; ++d) {
                short8 vf = *(const short8*)&Vt[d * 16 + l15][ks * 32 + lg * 8];
                oacc[d] = __builtin_amdgcn_mfma_f32_16x16x32_bf16(vf, pf, oacc[d], 0, 0, 0);
            }
            oext = __builtin_amdgcn_mfma_f32_16x16x32_bf16(vf5, pf, oext, 0, 0, 0);
        }
        __builtin_amdgcn_s_setprio(0);
    }

    float lsum = __shfl(oext[0], l15, 64);
    float inv = 1.0f / lsum;
    size_t ob = (size_t)(b * SEQ + qrow) * H_DIM + h * DKV;
    #pragma unroll
    for (int d = 0; d < 4; ++d) {
        ushort4 u;
        #pragma unroll
        for (int j = 0; j < 4; ++j)
            ((unsigned short*)&u)[j] = f32_bf16(oacc[d][j] * inv);
        *(ushort4*)&out[ob + d * 16 + lg * 4] = u;
    }
}

// ---------------- launch ----------------
extern "C" void kernel_launch(void* const* d_in, const int* in_sizes, int n_in,
                              void* d_out, int out_size, void* d_ws, size_t ws_size,
                              hipStream_t stream) {
    const float* x     = (const float*)d_in[0];
    const float* ln1w  = (const float*)d_in[1];
    const float* ln1b  = (const float*)d_in[2];
    const float* Wqkv  = (const float*)d_in[3];
    const float* bqkv  = (const float*)d_in[4];
    const float* Wo    = (const float*)d_in[5];
    const float* bo    = (const float*)d_in[6];
    const float* ln2w  = (const float*)d_in[7];
    const float* ln2b  = (const float*)d_in[8];
    const float* Wfc   = (const float*)d_in[9];
    const float* bfc   = (const float*)d_in[10];
    const float* Wproj = (const float*)d_in[11];
    const float* bproj = (const float*)d_in[12];
    float* out = (float*)d_out;

    char* ws = (char*)d_ws;
    size_t off = 0;
    auto take = [&](size_t bytes) {
        void* p = ws + off;
        off += (bytes + 255) & ~(size_t)255;
        return p;
    };

    unsigned short* WqT  = (unsigned short*)take((size_t)3072 * 1024 * 2);
    unsigned short* WoT  = (unsigned short*)take((size_t)1024 * 1024 * 2);
    unsigned short* WfcT = (unsigned short*)take((size_t)4096 * 1024 * 2);
    unsigned short* WpT  = (unsigned short*)take((size_t)1024 * 4096 * 2);
    unsigned short* xn1   = (unsigned short*)take((size_t)ROWS * 1024 * 2);
    unsigned short* qk_h  = (unsigned short*)take((size_t)ROWS * 2048 * 2);
    unsigned short* vT    = (unsigned short*)take((size_t)ROWS * 1024 * 2);
    unsigned short* attn  = (unsigned short*)take((size_t)ROWS * 1024 * 2);
    float*          x1    = (float*)take((size_t)ROWS * 1024 * 4);
    unsigned short* xn2   = (unsigned short*)take((size_t)ROWS * 1024 * 2);
    unsigned short* hbuf  = (unsigned short*)take((size_t)ROWS * 4096 * 2);

    // weight transposes fp32[K][N] -> bf16[N][K]
    transpose_bf16<<<dim3(3072 / 32, 1024 / 32), 256, 0, stream>>>(Wqkv,  WqT,  1024, 3072);
    transpose_bf16<<<dim3(1024 / 32, 1024 / 32), 256, 0, stream>>>(Wo,    WoT,  1024, 1024);
    transpose_bf16<<<dim3(4096 / 32, 1024 / 32), 256, 0, stream>>>(Wfc,   WfcT, 1024, 4096);
    transpose_bf16<<<dim3(1024 / 32, 4096 / 32), 256, 0, stream>>>(Wproj, WpT,  4096, 1024);

    // LN1 -> xn1 (bf16)
    ln_bf16<<<ROWS, 256, 0, stream>>>(x, ln1w, ln1b, xn1);

    // QKV: Q (pre-scaled) | K -> qk_h packed, V -> vT transposed   (grid 24x32 = 768)
    gemmT<4, 4><<<768, 512, 0, stream>>>(xn1, WqT, bqkv, nullptr, nullptr, qk_h, vT, 24, 3072, 1024);

    // causal attention -> attn (bf16), QBLK=128, grid 512
    attn_mfma<<<512, 512, 0, stream>>>(qk_h, vT, attn);

    // x1 = x + attn @ Wo + bo   (128x64 tile, grid 16x32 = 512)
    gemmT<1, 2><<<512, 512, 0, stream>>>(attn, WoT, bo, x, x1, nullptr, nullptr, 16, 1024, 1024);

    // LN2 -> xn2 (bf16)
    ln_bf16<<<ROWS, 256, 0, stream>>>(x1, ln2w, ln2b, xn2);

    // h = gelu(xn2 @ Wfc + bfc)   (grid 32x32 = 1024)
    gemmT<2, 4><<<1024, 512, 0, stream>>>(xn2, WfcT, bfc, nullptr, nullptr, hbuf, nullptr, 32, 4096, 1024);

    // out = x1 + h @ Wproj + bproj   (128x64 tile, grid 16x32 = 512)
    gemmT<1, 2><<<512, 512, 0, stream>>>(hbuf, WpT, bproj, x1, out, nullptr, nullptr, 16, 1024, 4096);
}

// Round 15
// 242.914 us; speedup vs baseline: 1.2245x; 1.0243x over previous
//
#include <hip/hip_runtime.h>
#include <hip/hip_bf16.h>
#include <math.h>

#define H_DIM 1024
#define SEQ   2048
#define BATCH 2
#define NHEAD 16
#define DKV   64
#define ROWS  (BATCH*SEQ)   // 4096
#define QSCALE 0.18033688f  // 0.125 * log2(e): scores land in log2 domain

typedef __attribute__((ext_vector_type(8))) short short8;
typedef __attribute__((ext_vector_type(4))) float f32x4;

static __device__ __forceinline__ unsigned short f32_bf16(float f) {
    unsigned int u = __builtin_bit_cast(unsigned int, f);
    u += 0x7FFF + ((u >> 16) & 1);          // RNE
    return (unsigned short)(u >> 16);
}

// A&S 7.1.26 rational-poly erf, |err| < 1.5e-7
static __device__ __forceinline__ float fast_erf(float x) {
    float ax = fabsf(x);
    float t = 1.0f / fmaf(0.3275911f, ax, 1.0f);
    float p = t * fmaf(t, fmaf(t, fmaf(t, fmaf(t, 1.061405429f, -1.453152027f),
                                       1.421413741f), -0.284496736f), 0.254829592f);
    float y = fmaf(-p, __expf(-ax * ax), 1.0f);
    return copysignf(y, x);
}

static __device__ __forceinline__ void gload16(const unsigned short* g, unsigned short* l) {
    __builtin_amdgcn_global_load_lds(
        (const __attribute__((address_space(1))) void*)g,
        (__attribute__((address_space(3))) void*)l,
        16, 0, 0);
}

// ---------------- fp32 [K][N] -> bf16 [N][K] transpose ----------------
__global__ __launch_bounds__(256) void transpose_bf16(const float* __restrict__ in,
                                                      unsigned short* __restrict__ out,
                                                      int K, int N) {
    __shared__ float tile[32][33];
    int n0 = blockIdx.x * 32, k0 = blockIdx.y * 32;
    int tx = threadIdx.x & 31, ty = threadIdx.x >> 5;   // 32 x 8
    #pragma unroll
    for (int i = 0; i < 4; ++i)
        tile[ty + i * 8][tx] = in[(size_t)(k0 + ty + i * 8) * N + n0 + tx];
    __syncthreads();
    #pragma unroll
    for (int i = 0; i < 4; ++i)
        out[(size_t)(n0 + ty + i * 8) * K + k0 + tx] = f32_bf16(tile[tx][ty + i * 8]);
}

// ---------------- LayerNorm (fp32 in -> bf16 out) ----------------
__global__ __launch_bounds__(256) void ln_bf16(const float* __restrict__ x,
                                               const float* __restrict__ w,
                                               const float* __restrict__ bb,
                                               unsigned short* __restrict__ out) {
    int row = blockIdx.x;
    int tid = threadIdx.x;
    float4 v = ((const float4*)(x + (size_t)row * H_DIM))[tid];
    float s  = v.x + v.y + v.z + v.w;
    float s2 = v.x*v.x + v.y*v.y + v.z*v.z + v.w*v.w;
    #pragma unroll
    for (int off = 1; off < 64; off <<= 1) {
        s  += __shfl_xor(s,  off, 64);
        s2 += __shfl_xor(s2, off, 64);
    }
    __shared__ float red[8];
    int wv = tid >> 6;
    if ((tid & 63) == 0) { red[wv] = s; red[4 + wv] = s2; }
    __syncthreads();
    s  = red[0] + red[1] + red[2] + red[3];
    s2 = red[4] + red[5] + red[6] + red[7];
    float mu = s * (1.0f / H_DIM);
    float rs = rsqrtf(s2 * (1.0f / H_DIM) - mu * mu + 1e-5f);
    float4 wv4 = ((const float4*)w)[tid];
    float4 bv4 = ((const float4*)bb)[tid];
    ushort4 o;
    o.x = f32_bf16((v.x - mu) * rs * wv4.x + bv4.x);
    o.y = f32_bf16((v.y - mu) * rs * wv4.y + bv4.y);
    o.z = f32_bf16((v.z - mu) * rs * wv4.z + bv4.z);
    o.w = f32_bf16((v.w - mu) * rs * wv4.w + bv4.w);
    ((ushort4*)(out + (size_t)row * H_DIM))[tid] = o;
}

// ======== epilogue helper ========
template<int EPI>
static __device__ __forceinline__ void epi_store(f32x4 a, int row0, int col, int N,
                                                 const float* __restrict__ bias,
                                                 const float* __restrict__ resid,
                                                 float* __restrict__ outF,
                                                 unsigned short* __restrict__ outH,
                                                 unsigned short* __restrict__ outH2) {
    float bv = bias[col];
    if (EPI == 4 && col >= 2048) {
        int bb = row0 >> 11, ss = row0 & 2047;
        int hd = col - 2048;
        ushort4 u;
        u.x = f32_bf16(a[0] + bv);
        u.y = f32_bf16(a[1] + bv);
        u.z = f32_bf16(a[2] + bv);
        u.w = f32_bf16(a[3] + bv);
        *(ushort4*)&outH2[((size_t)bb * 1024 + hd) * SEQ + ss] = u;
    } else {
        #pragma unroll
        for (int j = 0; j < 4; ++j) {
            int row = row0 + j;
            size_t idx = (size_t)row * N + col;
            float c = a[j] + bv;
            if (EPI == 0) {
                outF[idx] = c;
            } else if (EPI == 1) {
                outF[idx] = resid[idx] + c;
            } else if (EPI == 2) {
                float g = 0.5f * c * (1.0f + fast_erf(c * 0.70710678118f));
                outH[idx] = f32_bf16(g);
            } else if (EPI == 3) {
                outH[idx] = f32_bf16(c);
            } else {
                // Q|K packed; Q pre-scaled into log2-softmax domain
                float c2 = (col < 1024) ? c * QSCALE : c;
                outH[(size_t)row * 2048 + col] = f32_bf16(c2);
            }
        }
    }
}

// ---------------- bf16 MFMA GEMM, 128 x (NI*32) tile, BK=64, single-buffer,
//                  8 waves (512 thr), wave-tile 64 x (NI*8) (round-14 proven) ----------------
template<int EPI, int NI>
__global__ __launch_bounds__(512) void gemmT(const unsigned short* __restrict__ A,
                                             const unsigned short* __restrict__ Bt,
                                             const float* __restrict__ bias,
                                             const float* __restrict__ resid,
                                             float* __restrict__ outF,
                                             unsigned short* __restrict__ outH,
                                             unsigned short* __restrict__ outH2,
                                             int gx, int N, int K) {
    constexpr int BN = NI * 32;
    constexpr int WN = BN / 4;        // wave col-span: 32 or 16
    constexpr int NT = WN / 16;       // ni tiles per wave: 2 or 1
    __shared__ __attribute__((aligned(16))) unsigned short As[128][64];
    __shared__ __attribute__((aligned(16))) unsigned short Bs[BN][64];
    int tid = threadIdx.x;
    int w = tid >> 6, l = tid & 63;   // 8 waves
    int l15 = l & 15, lg = l >> 4;
    int wm = w & 1, wn = w >> 1;      // 2 (M) x 4 (N)

    int qq = gridDim.x >> 3;
    int wg = (blockIdx.x & 7) * qq + (blockIdx.x >> 3);
    int bm = wg / gx, bn = wg - bm * gx;
    int m0 = bm * 128, n0 = bn * BN;

    f32x4 acc[4][NT] = {};

    const unsigned short* aptr[2];
    unsigned short* lA[2];
    #pragma unroll
    for (int j = 0; j < 2; ++j) {
        int slot = j * 512 + tid;                 // 0..1023
        int row = slot >> 3;
        int lchunk = (slot & 7) ^ (row & 7);      // pre-swizzled source chunk
        aptr[j] = A + (size_t)(m0 + row) * K + lchunk * 8;
        lA[j] = &As[0][0] + (size_t)slot * 8 - l * 8;   // wave-uniform base (+lane*16B HW)
    }
    const unsigned short* bptr[NI / 2];
    unsigned short* lB[NI / 2];
    #pragma unroll
    for (int j = 0; j < NI / 2; ++j) {
        int slot = j * 512 + tid;
        int row = slot >> 3;
        int lchunk = (slot & 7) ^ (row & 7);
        bptr[j] = Bt + (size_t)(n0 + row) * K + lchunk * 8;
        lB[j] = &Bs[0][0] + (size_t)slot * 8 - l * 8;
    }
    int swz[2];
    swz[0] = ((0 + lg) ^ (l15 & 7)) * 8;
    swz[1] = ((4 + lg) ^ (l15 & 7)) * 8;
    const unsigned short* pA = &As[wm * 64 + l15][0];
    const unsigned short* pB = &Bs[wn * WN + l15][0];

    for (int k0 = 0; k0 < K; k0 += 64) {
        __syncthreads();
        #pragma unroll
        for (int j = 0; j < 2; ++j) gload16(aptr[j] + k0, lA[j]);
        #pragma unroll
        for (int j = 0; j < NI / 2; ++j) gload16(bptr[j] + k0, lB[j]);
        __syncthreads();

        #pragma unroll
        for (int ks = 0; ks < 2; ++ks) {
            short8 af[4], bf[NT];
            #pragma unroll
            for (int mi = 0; mi < 4; ++mi)
                af[mi] = *(const short8*)(pA + mi * 16 * 64 + swz[ks]);
            #pragma unroll
            for (int ni = 0; ni < NT; ++ni)
                bf[ni] = *(const short8*)(pB + ni * 16 * 64 + swz[ks]);
            #pragma unroll
            for (int mi = 0; mi < 4; ++mi)
                #pragma unroll
                for (int ni = 0; ni < NT; ++ni)
                    acc[mi][ni] = __builtin_amdgcn_mfma_f32_16x16x32_bf16(af[mi], bf[ni], acc[mi][ni], 0, 0, 0);
        }
    }

    #pragma unroll
    for (int mi = 0; mi < 4; ++mi)
        #pragma unroll
        for (int ni = 0; ni < NT; ++ni)
            epi_store<EPI>(acc[mi][ni], m0 + wm * 64 + mi * 16 + lg * 4,
                           n0 + wn * WN + ni * 16 + l15, N, bias, resid, outF, outH, outH2);
}

// ---------------- causal flash attention: QBLK=128, 8 waves, K/V double-buffered,
//                  XOR-swizzled [64][64] tiles, 1 barrier per K/V tile ----------------
__global__ __launch_bounds__(512) void attn_mfma(const unsigned short* __restrict__ qk,
                                                 const unsigned short* __restrict__ vT,
                                                 unsigned short* __restrict__ out) {
    int bid = blockIdx.x;
    int swz = (bid & 7) * 64 + (bid >> 3);    // 512 % 8 == 0 -> bijective
    int b  = swz >> 8;
    int h  = (swz >> 4) & 15;
    int qt = 15 - (swz & 15);                 // long blocks first
    int tid = threadIdx.x;
    int w = tid >> 6, l = tid & 63;
    int l15 = l & 15, lg = l >> 4;

    __shared__ __attribute__((aligned(16))) unsigned short Ks[2][64][64];
    __shared__ __attribute__((aligned(16))) unsigned short Vt[2][64][64];
    __shared__ __attribute__((aligned(16))) unsigned short Ps[8][16][72];

    int qrow = qt * 128 + w * 16 + l15;       // this lane's q row
    short8 qf[2];
    {
        const unsigned short* qp = qk + (size_t)(b * SEQ + qrow) * 2048 + h * DKV + lg * 8;
        qf[0] = *(const short8*)qp;
        qf[1] = *(const short8*)(qp + 32);
    }
    short8 vf5;
    #pragma unroll
    for (int i = 0; i < 8; ++i) vf5[i] = (l15 == 0) ? (short)0x3F80 : (short)0;

    // staging: thread handles (srow, logical chunk c=tid&7); LDS phys chunk = c ^ (srow&7)
    int srow = tid >> 3;                      // 0..63
    int scl  = (tid & 7) * 8;                 // logical column (global)
    int spc  = (((tid & 7) ^ (srow & 7)) * 8);// physical column (LDS)
    const unsigned short* kbase = qk + (size_t)(b * SEQ + srow) * 2048 + 1024 + h * DKV + scl;
    const unsigned short* vbase = vT + ((size_t)(b * NHEAD + h) * DKV + srow) * SEQ + scl;

    // read-side swizzled chunk offsets: phys = (logchunk ^ (l15&7))*8
    int rk0 = ((0 * 4 + lg) ^ (l15 & 7)) * 8;   // K dstep 0 / V ks 0
    int rk1 = ((1 * 4 + lg) ^ (l15 & 7)) * 8;   // K dstep 1 / V ks 1

    float m = -1e30f;
    f32x4 oacc[4] = {};
    f32x4 oext = {};

    int nt = 2 * qt + 2;                      // always even

    // prologue: tile 0 -> regs -> buf0; tile 1 -> regs; barrier
    short8 kr0 = *(const short8*)kbase;
    short8 vr0 = *(const short8*)vbase;
    *(short8*)&Ks[0][srow][spc] = kr0;
    *(short8*)&Vt[0][srow][spc] = vr0;
    short8 kr1 = *(const short8*)(kbase + (size_t)64 * 2048);
    short8 vr1 = *(const short8*)(vbase + 64);
    __syncthreads();

#define ATTN_COMPUTE(BUF, KT)                                                          \
    {                                                                                  \
        f32x4 sc[4] = {};                                                              \
        __builtin_amdgcn_s_setprio(1);                                                 \
        _Pragma("unroll")                                                              \
        for (int st = 0; st < 4; ++st) {                                               \
            short8 kf0 = *(const short8*)&Ks[BUF][st * 16 + l15][rk0];                 \
            sc[st] = __builtin_amdgcn_mfma_f32_16x16x32_bf16(kf0, qf[0], sc[st], 0, 0, 0); \
            short8 kf1 = *(const short8*)&Ks[BUF][st * 16 + l15][rk1];                 \
            sc[st] = __builtin_amdgcn_mfma_f32_16x16x32_bf16(kf1, qf[1], sc[st], 0, 0, 0); \
        }                                                                              \
        __builtin_amdgcn_s_setprio(0);                                                 \
        int klim = qrow - (KT) * 64;                                                   \
        float pv[4][4];                                                                \
        float pmax = -1e30f;                                                           \
        _Pragma("unroll")                                                              \
        for (int st = 0; st < 4; ++st) {                                               \
            _Pragma("unroll")                                                          \
            for (int j = 0; j < 4; ++j) {                                              \
                float s = sc[st][j];                                                   \
                if (st * 16 + lg * 4 + j > klim) s = -1e30f;                           \
                pv[st][j] = s;                                                         \
                pmax = fmaxf(pmax, s);                                                 \
            }                                                                          \
        }                                                                              \
        if (!__all(pmax - m <= 8.0f)) {                                                \
            float pr = fmaxf(pmax, __shfl_xor(pmax, 16, 64));                          \
            pr = fmaxf(pr, __shfl_xor(pr, 32, 64));                                    \
            float mn = fmaxf(m, pr);                                                   \
            float scl2 = exp2f(m - mn);                                                \
            _Pragma("unroll")                                                          \
            for (int d = 0; d < 4; ++d)                                                \
                _Pragma("unroll")                                                      \
                for (int j = 0; j < 4; ++j)                                            \
                    oacc[d][j] *= scl2;                                                \
            _Pragma("unroll")                                                          \
            for (int j = 0; j < 4; ++j) oext[j] *= scl2;                               \
            m = mn;                                                                    \
        }                                                                              \
        _Pragma("unroll")                                                              \
        for (int st = 0; st < 4; ++st) {                                               \
            float p0 = exp2f(pv[st][0] - m);                                           \
            float p1 = exp2f(pv[st][1] - m);                                           \
            float p2 = exp2f(pv[st][2] - m);                                           \
            float p3 = exp2f(pv[st][3] - m);                                           \
            unsigned int ua, ub;                                                       \
            asm("v_cvt_pk_bf16_f32 %0, %1, %2" : "=v"(ua) : "v"(p0), "v"(p1));         \
            asm("v_cvt_pk_bf16_f32 %0, %1, %2" : "=v"(ub) : "v"(p2), "v"(p3));         \
            uint2 u = make_uint2(ua, ub);                                              \
            *(uint2*)&Ps[w][l15][st * 16 + lg * 4] = u;                                \
        }                                                                              \
        __builtin_amdgcn_s_setprio(1);                                                 \
        _Pragma("unroll")                                                              \
        for (int ks = 0; ks < 2; ++ks) {                                               \
            short8 pf = *(const short8*)&Ps[w][l15][ks * 32 + lg * 8];                 \
            int rv = (ks == 0) ? rk0 : rk1;                                            \
            _Pragma("unroll")                                                          \
            for (int d = 0; d < 4; ++d) {                                              \
                short8 vf = *(const short8*)&Vt[BUF][d * 16 + l15][rv];                \
                oacc[d] = __builtin_amdgcn_mfma_f32_16x16x32_bf16(vf, pf, oacc[d], 0, 0, 0); \
            }                                                                          \
            oext = __builtin_amdgcn_mfma_f32_16x16x32_bf16(vf5, pf, oext, 0, 0, 0);    \
        }                                                                              \
        __builtin_amdgcn_s_setprio(0);                                                 \
    }

    for (int t = 0; t < nt; t += 2) {
        // tile t (buf0): write tile t+1 into buf1 (its readers done before last bar)
        *(short8*)&Ks[1][srow][spc] = kr1;
        *(short8*)&Vt[1][srow][spc] = vr1;
        if (t + 2 < nt) {
            kr0 = *(const short8*)(kbase + (size_t)(t + 2) * 64 * 2048);
            vr0 = *(const short8*)(vbase + (t + 2) * 64);
        }
        ATTN_COMPUTE(0, t);
        __syncthreads();
        // tile t+1 (buf1): write tile t+2 into buf0 (read in compute(t), bar'ed)
        if (t + 2 < nt) {
            *(short8*)&Ks[0][srow][spc] = kr0;
            *(short8*)&Vt[0][srow][spc] = vr0;
            kr1 = *(const short8*)(kbase + (size_t)(t + 3) * 64 * 2048);
            vr1 = *(const short8*)(vbase + (t + 3) * 64);
        }
        ATTN_COMPUTE(1, t + 1);
        __syncthreads();
    }
#undef ATTN_COMPUTE

    float lsum = __shfl(oext[0], l15, 64);
    float inv = 1.0f / lsum;
    size_t ob = (size_t)(b * SEQ + qrow) * H_DIM + h * DKV;
    #pragma unroll
    for (int d = 0; d < 4; ++d) {
        ushort4 u;
        #pragma unroll
        for (int j = 0; j < 4; ++j)
            ((unsigned short*)&u)[j] = f32_bf16(oacc[d][j] * inv);
        *(ushort4*)&out[ob + d * 16 + lg * 4] = u;
    }
}

// ---------------- launch ----------------
extern "C" void kernel_launch(void* const* d_in, const int* in_sizes, int n_in,
                              void* d_out, int out_size, void* d_ws, size_t ws_size,
                              hipStream_t stream) {
    const float* x     = (const float*)d_in[0];
    const float* ln1w  = (const float*)d_in[1];
    const float* ln1b  = (const float*)d_in[2];
    const float* Wqkv  = (const float*)d_in[3];
    const float* bqkv  = (const float*)d_in[4];
    const float* Wo    = (const float*)d_in[5];
    const float* bo    = (const float*)d_in[6];
    const float* ln2w  = (const float*)d_in[7];
    const float* ln2b  = (const float*)d_in[8];
    const float* Wfc   = (const float*)d_in[9];
    const float* bfc   = (const float*)d_in[10];
    const float* Wproj = (const float*)d_in[11];
    const float* bproj = (const float*)d_in[12];
    float* out = (float*)d_out;

    char* ws = (char*)d_ws;
    size_t off = 0;
    auto take = [&](size_t bytes) {
        void* p = ws + off;
        off += (bytes + 255) & ~(size_t)255;
        return p;
    };

    unsigned short* WqT  = (unsigned short*)take((size_t)3072 * 1024 * 2);
    unsigned short* WoT  = (unsigned short*)take((size_t)1024 * 1024 * 2);
    unsigned short* WfcT = (unsigned short*)take((size_t)4096 * 1024 * 2);
    unsigned short* WpT  = (unsigned short*)take((size_t)1024 * 4096 * 2);
    unsigned short* xn1   = (unsigned short*)take((size_t)ROWS * 1024 * 2);
    unsigned short* qk_h  = (unsigned short*)take((size_t)ROWS * 2048 * 2);
    unsigned short* vT    = (unsigned short*)take((size_t)ROWS * 1024 * 2);
    unsigned short* attn  = (unsigned short*)take((size_t)ROWS * 1024 * 2);
    float*          x1    = (float*)take((size_t)ROWS * 1024 * 4);
    unsigned short* xn2   = (unsigned short*)take((size_t)ROWS * 1024 * 2);
    unsigned short* hbuf  = (unsigned short*)take((size_t)ROWS * 4096 * 2);

    // weight transposes fp32[K][N] -> bf16[N][K]
    transpose_bf16<<<dim3(3072 / 32, 1024 / 32), 256, 0, stream>>>(Wqkv,  WqT,  1024, 3072);
    transpose_bf16<<<dim3(1024 / 32, 1024 / 32), 256, 0, stream>>>(Wo,    WoT,  1024, 1024);
    transpose_bf16<<<dim3(4096 / 32, 1024 / 32), 256, 0, stream>>>(Wfc,   WfcT, 1024, 4096);
    transpose_bf16<<<dim3(1024 / 32, 4096 / 32), 256, 0, stream>>>(Wproj, WpT,  4096, 1024);

    // LN1 -> xn1 (bf16)
    ln_bf16<<<ROWS, 256, 0, stream>>>(x, ln1w, ln1b, xn1);

    // QKV: Q (pre-scaled) | K -> qk_h packed, V -> vT transposed   (grid 24x32 = 768)
    gemmT<4, 4><<<768, 512, 0, stream>>>(xn1, WqT, bqkv, nullptr, nullptr, qk_h, vT, 24, 3072, 1024);

    // causal attention -> attn (bf16), QBLK=128, grid 512
    attn_mfma<<<512, 512, 0, stream>>>(qk_h, vT, attn);

    // x1 = x + attn @ Wo + bo   (128x64 tile, grid 16x32 = 512)
    gemmT<1, 2><<<512, 512, 0, stream>>>(attn, WoT, bo, x, x1, nullptr, nullptr, 16, 1024, 1024);

    // LN2 -> xn2 (bf16)
    ln_bf16<<<ROWS, 256, 0, stream>>>(x1, ln2w, ln2b, xn2);

    // h = gelu(xn2 @ Wfc + bfc)   (grid 32x32 = 1024)
    gemmT<2, 4><<<1024, 512, 0, stream>>>(xn2, WfcT, bfc, nullptr, nullptr, hbuf, nullptr, 32, 4096, 1024);

    // out = x1 + h @ Wproj + bproj   (128x64 tile, grid 16x32 = 512)
    gemmT<1, 2><<<512, 512, 0, stream>>>(hbuf, WpT, bproj, x1, out, nullptr, nullptr, 16, 1024, 4096);
}

// Round 16
// 238.064 us; speedup vs baseline: 1.2495x; 1.0204x over previous
//
#include <hip/hip_runtime.h>
#include <hip/hip_bf16.h>
#include <math.h>

#define H_DIM 1024
#define SEQ   2048
#define BATCH 2
#define NHEAD 16
#define DKV   64
#define ROWS  (BATCH*SEQ)   // 4096
#define QSCALE 0.18033688f  // 0.125 * log2(e): scores land in log2 domain

typedef __attribute__((ext_vector_type(8))) short short8;
typedef __attribute__((ext_vector_type(4))) float f32x4;

static __device__ __forceinline__ unsigned short f32_bf16(float f) {
    unsigned int u = __builtin_bit_cast(unsigned int, f);
    u += 0x7FFF + ((u >> 16) & 1);          // RNE
    return (unsigned short)(u >> 16);
}
static __device__ __forceinline__ float bf16_f32(unsigned short h) {
    return __builtin_bit_cast(float, (unsigned int)h << 16);
}

// A&S 7.1.26 rational-poly erf, |err| < 1.5e-7
static __device__ __forceinline__ float fast_erf(float x) {
    float ax = fabsf(x);
    float t = 1.0f / fmaf(0.3275911f, ax, 1.0f);
    float p = t * fmaf(t, fmaf(t, fmaf(t, fmaf(t, 1.061405429f, -1.453152027f),
                                       1.421413741f), -0.284496736f), 0.254829592f);
    float y = fmaf(-p, __expf(-ax * ax), 1.0f);
    return copysignf(y, x);
}

static __device__ __forceinline__ void gload16(const unsigned short* g, unsigned short* l) {
    __builtin_amdgcn_global_load_lds(
        (const __attribute__((address_space(1))) void*)g,
        (__attribute__((address_space(3))) void*)l,
        16, 0, 0);
}

// ---------------- fp32 [K][N] -> bf16 [N][K] transpose ----------------
__global__ __launch_bounds__(256) void transpose_bf16(const float* __restrict__ in,
                                                      unsigned short* __restrict__ out,
                                                      int K, int N) {
    __shared__ float tile[32][33];
    int n0 = blockIdx.x * 32, k0 = blockIdx.y * 32;
    int tx = threadIdx.x & 31, ty = threadIdx.x >> 5;   // 32 x 8
    #pragma unroll
    for (int i = 0; i < 4; ++i)
        tile[ty + i * 8][tx] = in[(size_t)(k0 + ty + i * 8) * N + n0 + tx];
    __syncthreads();
    #pragma unroll
    for (int i = 0; i < 4; ++i)
        out[(size_t)(n0 + ty + i * 8) * K + k0 + tx] = f32_bf16(tile[tx][ty + i * 8]);
}

// ---------------- LayerNorm (fp32 or bf16 in -> bf16 out) ----------------
template<int BF16IN>
__global__ __launch_bounds__(256) void ln_any(const void* __restrict__ xin,
                                              const float* __restrict__ w,
                                              const float* __restrict__ bb,
                                              unsigned short* __restrict__ out) {
    int row = blockIdx.x;
    int tid = threadIdx.x;
    float4 v;
    if (BF16IN) {
        ushort4 u = ((const ushort4*)((const unsigned short*)xin + (size_t)row * H_DIM))[tid];
        v.x = bf16_f32(u.x); v.y = bf16_f32(u.y); v.z = bf16_f32(u.z); v.w = bf16_f32(u.w);
    } else {
        v = ((const float4*)((const float*)xin + (size_t)row * H_DIM))[tid];
    }
    float s  = v.x + v.y + v.z + v.w;
    float s2 = v.x*v.x + v.y*v.y + v.z*v.z + v.w*v.w;
    #pragma unroll
    for (int off = 1; off < 64; off <<= 1) {
        s  += __shfl_xor(s,  off, 64);
        s2 += __shfl_xor(s2, off, 64);
    }
    __shared__ float red[8];
    int wv = tid >> 6;
    if ((tid & 63) == 0) { red[wv] = s; red[4 + wv] = s2; }
    __syncthreads();
    s  = red[0] + red[1] + red[2] + red[3];
    s2 = red[4] + red[5] + red[6] + red[7];
    float mu = s * (1.0f / H_DIM);
    float rs = rsqrtf(s2 * (1.0f / H_DIM) - mu * mu + 1e-5f);
    float4 wv4 = ((const float4*)w)[tid];
    float4 bv4 = ((const float4*)bb)[tid];
    ushort4 o;
    o.x = f32_bf16((v.x - mu) * rs * wv4.x + bv4.x);
    o.y = f32_bf16((v.y - mu) * rs * wv4.y + bv4.y);
    o.z = f32_bf16((v.z - mu) * rs * wv4.z + bv4.z);
    o.w = f32_bf16((v.w - mu) * rs * wv4.w + bv4.w);
    ((ushort4*)(out + (size_t)row * H_DIM))[tid] = o;
}

// ======== epilogue helper ========
// EPI 0: outF = acc+bias (fp32)           EPI 1: outF = resid + acc+bias (fp32)
// EPI 2: outH = bf16(gelu(acc+bias))      EPI 3: outH = bf16(acc+bias)
// EPI 4: QKV split (Q scaled | K packed, V transposed to outH2)
// EPI 5: outH = bf16(resid_f32 + acc+bias)          (bf16 residual write)
// EPI 6: outF = bf16resid(outH2) + acc+bias (fp32)  (bf16 residual read)
template<int EPI>
static __device__ __forceinline__ void epi_store(f32x4 a, int row0, int col, int N,
                                                 const float* __restrict__ bias,
                                                 const float* __restrict__ resid,
                                                 float* __restrict__ outF,
                                                 unsigned short* __restrict__ outH,
                                                 unsigned short* __restrict__ outH2) {
    float bv = bias[col];
    if (EPI == 4 && col >= 2048) {
        int bb = row0 >> 11, ss = row0 & 2047;
        int hd = col - 2048;
        ushort4 u;
        u.x = f32_bf16(a[0] + bv);
        u.y = f32_bf16(a[1] + bv);
        u.z = f32_bf16(a[2] + bv);
        u.w = f32_bf16(a[3] + bv);
        *(ushort4*)&outH2[((size_t)bb * 1024 + hd) * SEQ + ss] = u;
    } else {
        #pragma unroll
        for (int j = 0; j < 4; ++j) {
            int row = row0 + j;
            size_t idx = (size_t)row * N + col;
            float c = a[j] + bv;
            if (EPI == 0) {
                outF[idx] = c;
            } else if (EPI == 1) {
                outF[idx] = resid[idx] + c;
            } else if (EPI == 2) {
                float g = 0.5f * c * (1.0f + fast_erf(c * 0.70710678118f));
                outH[idx] = f32_bf16(g);
            } else if (EPI == 3) {
                outH[idx] = f32_bf16(c);
            } else if (EPI == 5) {
                outH[idx] = f32_bf16(resid[idx] + c);
            } else if (EPI == 6) {
                outF[idx] = bf16_f32(outH2[idx]) + c;
            } else {
                // Q|K packed; Q pre-scaled into log2-softmax domain
                float c2 = (col < 1024) ? c * QSCALE : c;
                outH[(size_t)row * 2048 + col] = f32_bf16(c2);
            }
        }
    }
}

// ---------------- bf16 MFMA GEMM, 128 x (NI*32) tile, BK=64, single-buffer,
//                  8 waves (512 thr), wave-tile 64 x (NI*8) (round-14 proven) ----------------
template<int EPI, int NI>
__global__ __launch_bounds__(512) void gemmT(const unsigned short* __restrict__ A,
                                             const unsigned short* __restrict__ Bt,
                                             const float* __restrict__ bias,
                                             const float* __restrict__ resid,
                                             float* __restrict__ outF,
                                             unsigned short* __restrict__ outH,
                                             unsigned short* __restrict__ outH2,
                                             int gx, int N, int K) {
    constexpr int BN = NI * 32;
    constexpr int WN = BN / 4;        // wave col-span: 32 or 16
    constexpr int NT = WN / 16;       // ni tiles per wave: 2 or 1
    __shared__ __attribute__((aligned(16))) unsigned short As[128][64];
    __shared__ __attribute__((aligned(16))) unsigned short Bs[BN][64];
    int tid = threadIdx.x;
    int w = tid >> 6, l = tid & 63;   // 8 waves
    int l15 = l & 15, lg = l >> 4;
    int wm = w & 1, wn = w >> 1;      // 2 (M) x 4 (N)

    int qq = gridDim.x >> 3;
    int wg = (blockIdx.x & 7) * qq + (blockIdx.x >> 3);
    int bm = wg / gx, bn = wg - bm * gx;
    int m0 = bm * 128, n0 = bn * BN;

    f32x4 acc[4][NT] = {};

    const unsigned short* aptr[2];
    unsigned short* lA[2];
    #pragma unroll
    for (int j = 0; j < 2; ++j) {
        int slot = j * 512 + tid;                 // 0..1023
        int row = slot >> 3;
        int lchunk = (slot & 7) ^ (row & 7);      // pre-swizzled source chunk
        aptr[j] = A + (size_t)(m0 + row) * K + lchunk * 8;
        lA[j] = &As[0][0] + (size_t)slot * 8 - l * 8;   // wave-uniform base (+lane*16B HW)
    }
    const unsigned short* bptr[NI / 2];
    unsigned short* lB[NI / 2];
    #pragma unroll
    for (int j = 0; j < NI / 2; ++j) {
        int slot = j * 512 + tid;
        int row = slot >> 3;
        int lchunk = (slot & 7) ^ (row & 7);
        bptr[j] = Bt + (size_t)(n0 + row) * K + lchunk * 8;
        lB[j] = &Bs[0][0] + (size_t)slot * 8 - l * 8;
    }
    int swz[2];
    swz[0] = ((0 + lg) ^ (l15 & 7)) * 8;
    swz[1] = ((4 + lg) ^ (l15 & 7)) * 8;
    const unsigned short* pA = &As[wm * 64 + l15][0];
    const unsigned short* pB = &Bs[wn * WN + l15][0];

    for (int k0 = 0; k0 < K; k0 += 64) {
        __syncthreads();
        #pragma unroll
        for (int j = 0; j < 2; ++j) gload16(aptr[j] + k0, lA[j]);
        #pragma unroll
        for (int j = 0; j < NI / 2; ++j) gload16(bptr[j] + k0, lB[j]);
        __syncthreads();

        #pragma unroll
        for (int ks = 0; ks < 2; ++ks) {
            short8 af[4], bf[NT];
            #pragma unroll
            for (int mi = 0; mi < 4; ++mi)
                af[mi] = *(const short8*)(pA + mi * 16 * 64 + swz[ks]);
            #pragma unroll
            for (int ni = 0; ni < NT; ++ni)
                bf[ni] = *(const short8*)(pB + ni * 16 * 64 + swz[ks]);
            #pragma unroll
            for (int mi = 0; mi < 4; ++mi)
                #pragma unroll
                for (int ni = 0; ni < NT; ++ni)
                    acc[mi][ni] = __builtin_amdgcn_mfma_f32_16x16x32_bf16(af[mi], bf[ni], acc[mi][ni], 0, 0, 0);
        }
    }

    #pragma unroll
    for (int mi = 0; mi < 4; ++mi)
        #pragma unroll
        for (int ni = 0; ni < NT; ++ni)
            epi_store<EPI>(acc[mi][ni], m0 + wm * 64 + mi * 16 + lg * 4,
                           n0 + wn * WN + ni * 16 + l15, N, bias, resid, outF, outH, outH2);
}

// ---------------- causal flash attention: QBLK=128, 8 waves, K/V double-buffered,
//                  XOR-swizzled [64][64] tiles, 1 barrier/tile, wave-uniform mask skip ----
__global__ __launch_bounds__(512) void attn_mfma(const unsigned short* __restrict__ qk,
                                                 const unsigned short* __restrict__ vT,
                                                 unsigned short* __restrict__ out) {
    int bid = blockIdx.x;
    int swz = (bid & 7) * 64 + (bid >> 3);    // 512 % 8 == 0 -> bijective
    int b  = swz >> 8;
    int h  = (swz >> 4) & 15;
    int qt = 15 - (swz & 15);                 // long blocks first
    int tid = threadIdx.x;
    int w = tid >> 6, l = tid & 63;
    int l15 = l & 15, lg = l >> 4;

    __shared__ __attribute__((aligned(16))) unsigned short Ks[2][64][64];
    __shared__ __attribute__((aligned(16))) unsigned short Vt[2][64][64];
    __shared__ __attribute__((aligned(16))) unsigned short Ps[8][16][72];

    int qrow = qt * 128 + w * 16 + l15;       // this lane's q row
    short8 qf[2];
    {
        const unsigned short* qp = qk + (size_t)(b * SEQ + qrow) * 2048 + h * DKV + lg * 8;
        qf[0] = *(const short8*)qp;
        qf[1] = *(const short8*)(qp + 32);
    }
    short8 vf5;
    #pragma unroll
    for (int i = 0; i < 8; ++i) vf5[i] = (l15 == 0) ? (short)0x3F80 : (short)0;

    int srow = tid >> 3;                      // 0..63
    int scl  = (tid & 7) * 8;                 // logical column (global)
    int spc  = (((tid & 7) ^ (srow & 7)) * 8);// physical column (LDS)
    const unsigned short* kbase = qk + (size_t)(b * SEQ + srow) * 2048 + 1024 + h * DKV + scl;
    const unsigned short* vbase = vT + ((size_t)(b * NHEAD + h) * DKV + srow) * SEQ + scl;

    int rk0 = ((0 * 4 + lg) ^ (l15 & 7)) * 8;
    int rk1 = ((1 * 4 + lg) ^ (l15 & 7)) * 8;

    float m = -1e30f;
    f32x4 oacc[4] = {};
    f32x4 oext = {};

    int nt = 2 * qt + 2;                      // always even

    short8 kr0 = *(const short8*)kbase;
    short8 vr0 = *(const short8*)vbase;
    *(short8*)&Ks[0][srow][spc] = kr0;
    *(short8*)&Vt[0][srow][spc] = vr0;
    short8 kr1 = *(const short8*)(kbase + (size_t)64 * 2048);
    short8 vr1 = *(const short8*)(vbase + 64);
    __syncthreads();

#define ATTN_COMPUTE(BUF, KT)                                                          \
    {                                                                                  \
        f32x4 sc[4] = {};                                                              \
        __builtin_amdgcn_s_setprio(1);                                                 \
        _Pragma("unroll")                                                              \
        for (int st = 0; st < 4; ++st) {                                               \
            short8 kf0 = *(const short8*)&Ks[BUF][st * 16 + l15][rk0];                 \
            sc[st] = __builtin_amdgcn_mfma_f32_16x16x32_bf16(kf0, qf[0], sc[st], 0, 0, 0); \
            short8 kf1 = *(const short8*)&Ks[BUF][st * 16 + l15][rk1];                 \
            sc[st] = __builtin_amdgcn_mfma_f32_16x16x32_bf16(kf1, qf[1], sc[st], 0, 0, 0); \
        }                                                                              \
        __builtin_amdgcn_s_setprio(0);                                                 \
        float pv[4][4];                                                                \
        float pmax = -1e30f;                                                           \
        bool needmask = ((KT) * 64 + 63) > (qt * 128 + w * 16);   /* wave-uniform */   \
        if (needmask) {                                                                \
            int klim = qrow - (KT) * 64;                                               \
            _Pragma("unroll")                                                          \
            for (int st = 0; st < 4; ++st) {                                           \
                _Pragma("unroll")                                                      \
                for (int j = 0; j < 4; ++j) {                                          \
                    float s = sc[st][j];                                               \
                    if (st * 16 + lg * 4 + j > klim) s = -1e30f;                       \
                    pv[st][j] = s;                                                     \
                    pmax = fmaxf(pmax, s);                                             \
                }                                                                      \
            }                                                                          \
        } else {                                                                       \
            _Pragma("unroll")                                                          \
            for (int st = 0; st < 4; ++st) {                                           \
                _Pragma("unroll")                                                      \
                for (int j = 0; j < 4; ++j) {                                          \
                    pv[st][j] = sc[st][j];                                             \
                    pmax = fmaxf(pmax, sc[st][j]);                                     \
                }                                                                      \
            }                                                                          \
        }                                                                              \
        if (!__all(pmax - m <= 8.0f)) {                                                \
            float pr = fmaxf(pmax, __shfl_xor(pmax, 16, 64));                          \
            pr = fmaxf(pr, __shfl_xor(pr, 32, 64));                                    \
            float mn = fmaxf(m, pr);                                                   \
            float scl2 = exp2f(m - mn);                                                \
            _Pragma("unroll")                                                          \
            for (int d = 0; d < 4; ++d)                                                \
                _Pragma("unroll")                                                      \
                for (int j = 0; j < 4; ++j)                                            \
                    oacc[d][j] *= scl2;                                                \
            _Pragma("unroll")                                                          \
            for (int j = 0; j < 4; ++j) oext[j] *= scl2;                               \
            m = mn;                                                                    \
        }                                                                              \
        _Pragma("unroll")                                                              \
        for (int st = 0; st < 4; ++st) {                                               \
            float p0 = exp2f(pv[st][0] - m);                                           \
            float p1 = exp2f(pv[st][1] - m);                                           \
            float p2 = exp2f(pv[st][2] - m);                                           \
            float p3 = exp2f(pv[st][3] - m);                                           \
            unsigned int ua, ub;                                                       \
            asm("v_cvt_pk_bf16_f32 %0, %1, %2" : "=v"(ua) : "v"(p0), "v"(p1));         \
            asm("v_cvt_pk_bf16_f32 %0, %1, %2" : "=v"(ub) : "v"(p2), "v"(p3));         \
            uint2 u = make_uint2(ua, ub);                                              \
            *(uint2*)&Ps[w][l15][st * 16 + lg * 4] = u;                                \
        }                                                                              \
        __builtin_amdgcn_s_setprio(1);                                                 \
        _Pragma("unroll")                                                              \
        for (int ks = 0; ks < 2; ++ks) {                                               \
            short8 pf = *(const short8*)&Ps[w][l15][ks * 32 + lg * 8];                 \
            int rv = (ks == 0) ? rk0 : rk1;                                            \
            _Pragma("unroll")                                                          \
            for (int d = 0; d < 4; ++d) {                                              \
                short8 vf = *(const short8*)&Vt[BUF][d * 16 + l15][rv];                \
                oacc[d] = __builtin_amdgcn_mfma_f32_16x16x32_bf16(vf, pf, oacc[d], 0, 0, 0); \
            }                                                                          \
            oext = __builtin_amdgcn_mfma_f32_16x16x32_bf16(vf5, pf, oext, 0, 0, 0);    \
        }                                                                              \
        __builtin_amdgcn_s_setprio(0);                                                 \
    }

    for (int t = 0; t < nt; t += 2) {
        *(short8*)&Ks[1][srow][spc] = kr1;
        *(short8*)&Vt[1][srow][spc] = vr1;
        if (t + 2 < nt) {
            kr0 = *(const short8*)(kbase + (size_t)(t + 2) * 64 * 2048);
            vr0 = *(const short8*)(vbase + (t + 2) * 64);
        }
        ATTN_COMPUTE(0, t);
        __syncthreads();
        if (t + 2 < nt) {
            *(short8*)&Ks[0][srow][spc] = kr0;
            *(short8*)&Vt[0][srow][spc] = vr0;
            kr1 = *(const short8*)(kbase + (size_t)(t + 3) * 64 * 2048);
            vr1 = *(const short8*)(vbase + (t + 3) * 64);
        }
        ATTN_COMPUTE(1, t + 1);
        __syncthreads();
    }
#undef ATTN_COMPUTE

    float lsum = __shfl(oext[0], l15, 64);
    float inv = 1.0f / lsum;
    size_t ob = (size_t)(b * SEQ + qrow) * H_DIM + h * DKV;
    #pragma unroll
    for (int d = 0; d < 4; ++d) {
        ushort4 u;
        #pragma unroll
        for (int j = 0; j < 4; ++j)
            ((unsigned short*)&u)[j] = f32_bf16(oacc[d][j] * inv);
        *(ushort4*)&out[ob + d * 16 + lg * 4] = u;
    }
}

// ---------------- launch ----------------
extern "C" void kernel_launch(void* const* d_in, const int* in_sizes, int n_in,
                              void* d_out, int out_size, void* d_ws, size_t ws_size,
                              hipStream_t stream) {
    const float* x     = (const float*)d_in[0];
    const float* ln1w  = (const float*)d_in[1];
    const float* ln1b  = (const float*)d_in[2];
    const float* Wqkv  = (const float*)d_in[3];
    const float* bqkv  = (const float*)d_in[4];
    const float* Wo    = (const float*)d_in[5];
    const float* bo    = (const float*)d_in[6];
    const float* ln2w  = (const float*)d_in[7];
    const float* ln2b  = (const float*)d_in[8];
    const float* Wfc   = (const float*)d_in[9];
    const float* bfc   = (const float*)d_in[10];
    const float* Wproj = (const float*)d_in[11];
    const float* bproj = (const float*)d_in[12];
    float* out = (float*)d_out;

    char* ws = (char*)d_ws;
    size_t off = 0;
    auto take = [&](size_t bytes) {
        void* p = ws + off;
        off += (bytes + 255) & ~(size_t)255;
        return p;
    };

    unsigned short* WqT  = (unsigned short*)take((size_t)3072 * 1024 * 2);
    unsigned short* WoT  = (unsigned short*)take((size_t)1024 * 1024 * 2);
    unsigned short* WfcT = (unsigned short*)take((size_t)4096 * 1024 * 2);
    unsigned short* WpT  = (unsigned short*)take((size_t)1024 * 4096 * 2);
    unsigned short* xn1   = (unsigned short*)take((size_t)ROWS * 1024 * 2);
    unsigned short* qk_h  = (unsigned short*)take((size_t)ROWS * 2048 * 2);
    unsigned short* vT    = (unsigned short*)take((size_t)ROWS * 1024 * 2);
    unsigned short* attn  = (unsigned short*)take((size_t)ROWS * 1024 * 2);
    unsigned short* x1h   = (unsigned short*)take((size_t)ROWS * 1024 * 2);   // bf16 residual
    unsigned short* xn2   = (unsigned short*)take((size_t)ROWS * 1024 * 2);
    unsigned short* hbuf  = (unsigned short*)take((size_t)ROWS * 4096 * 2);

    // weight transposes fp32[K][N] -> bf16[N][K]
    transpose_bf16<<<dim3(3072 / 32, 1024 / 32), 256, 0, stream>>>(Wqkv,  WqT,  1024, 3072);
    transpose_bf16<<<dim3(1024 / 32, 1024 / 32), 256, 0, stream>>>(Wo,    WoT,  1024, 1024);
    transpose_bf16<<<dim3(4096 / 32, 1024 / 32), 256, 0, stream>>>(Wfc,   WfcT, 1024, 4096);
    transpose_bf16<<<dim3(1024 / 32, 4096 / 32), 256, 0, stream>>>(Wproj, WpT,  4096, 1024);

    // LN1 (fp32 in) -> xn1
    ln_any<0><<<ROWS, 256, 0, stream>>>(x, ln1w, ln1b, xn1);

    // QKV: Q (pre-scaled) | K -> qk_h packed, V -> vT transposed   (grid 24x32 = 768)
    gemmT<4, 4><<<768, 512, 0, stream>>>(xn1, WqT, bqkv, nullptr, nullptr, qk_h, vT, 24, 3072, 1024);

    // causal attention -> attn (bf16), QBLK=128, grid 512
    attn_mfma<<<512, 512, 0, stream>>>(qk_h, vT, attn);

    // x1h = bf16(x + attn @ Wo + bo)   (128x64 tile, grid 512)
    gemmT<5, 2><<<512, 512, 0, stream>>>(attn, WoT, bo, x, nullptr, x1h, nullptr, 16, 1024, 1024);

    // LN2 (bf16 in) -> xn2
    ln_any<1><<<ROWS, 256, 0, stream>>>(x1h, ln2w, ln2b, xn2);

    // h = gelu(xn2 @ Wfc + bfc)   (grid 32x32 = 1024)
    gemmT<2, 4><<<1024, 512, 0, stream>>>(xn2, WfcT, bfc, nullptr, nullptr, hbuf, nullptr, 32, 4096, 1024);

    // out = x1h + h @ Wproj + bproj   (128x64 tile, grid 512; resid read bf16 via outH2)
    gemmT<6, 2><<<512, 512, 0, stream>>>(hbuf, WpT, bproj, nullptr, out, nullptr, x1h, 16, 1024, 4096);
}

// Round 17
// 220.840 us; speedup vs baseline: 1.3469x; 1.0780x over previous
//
#include <hip/hip_runtime.h>
#include <hip/hip_bf16.h>
#include <math.h>

#define H_DIM 1024
#define SEQ   2048
#define BATCH 2
#define NHEAD 16
#define DKV   64
#define ROWS  (BATCH*SEQ)   // 4096
#define QSCALE 0.18033688f  // 0.125 * log2(e): scores land in log2 domain

typedef __attribute__((ext_vector_type(8))) short short8;
typedef __attribute__((ext_vector_type(4))) float f32x4;

static __device__ __forceinline__ unsigned short f32_bf16(float f) {
    unsigned int u = __builtin_bit_cast(unsigned int, f);
    u += 0x7FFF + ((u >> 16) & 1);          // RNE
    return (unsigned short)(u >> 16);
}
static __device__ __forceinline__ float bf16_f32(unsigned short h) {
    return __builtin_bit_cast(float, (unsigned int)h << 16);
}

// A&S 7.1.26 rational-poly erf, |err| < 1.5e-7
static __device__ __forceinline__ float fast_erf(float x) {
    float ax = fabsf(x);
    float t = 1.0f / fmaf(0.3275911f, ax, 1.0f);
    float p = t * fmaf(t, fmaf(t, fmaf(t, fmaf(t, 1.061405429f, -1.453152027f),
                                       1.421413741f), -0.284496736f), 0.254829592f);
    float y = fmaf(-p, __expf(-ax * ax), 1.0f);
    return copysignf(y, x);
}

static __device__ __forceinline__ void gload16(const unsigned short* g, unsigned short* l) {
    __builtin_amdgcn_global_load_lds(
        (const __attribute__((address_space(1))) void*)g,
        (__attribute__((address_space(3))) void*)l,
        16, 0, 0);
}

// ---------------- fp32 [K][N] -> bf16 [N][K] transpose ----------------
__global__ __launch_bounds__(256) void transpose_bf16(const float* __restrict__ in,
                                                      unsigned short* __restrict__ out,
                                                      int K, int N) {
    __shared__ float tile[32][33];
    int n0 = blockIdx.x * 32, k0 = blockIdx.y * 32;
    int tx = threadIdx.x & 31, ty = threadIdx.x >> 5;   // 32 x 8
    #pragma unroll
    for (int i = 0; i < 4; ++i)
        tile[ty + i * 8][tx] = in[(size_t)(k0 + ty + i * 8) * N + n0 + tx];
    __syncthreads();
    #pragma unroll
    for (int i = 0; i < 4; ++i)
        out[(size_t)(n0 + ty + i * 8) * K + k0 + tx] = f32_bf16(tile[tx][ty + i * 8]);
}

// ---------------- LayerNorm (fp32 or bf16 in -> bf16 out) ----------------
template<int BF16IN>
__global__ __launch_bounds__(256) void ln_any(const void* __restrict__ xin,
                                              const float* __restrict__ w,
                                              const float* __restrict__ bb,
                                              unsigned short* __restrict__ out) {
    int row = blockIdx.x;
    int tid = threadIdx.x;
    float4 v;
    if (BF16IN) {
        ushort4 u = ((const ushort4*)((const unsigned short*)xin + (size_t)row * H_DIM))[tid];
        v.x = bf16_f32(u.x); v.y = bf16_f32(u.y); v.z = bf16_f32(u.z); v.w = bf16_f32(u.w);
    } else {
        v = ((const float4*)((const float*)xin + (size_t)row * H_DIM))[tid];
    }
    float s  = v.x + v.y + v.z + v.w;
    float s2 = v.x*v.x + v.y*v.y + v.z*v.z + v.w*v.w;
    #pragma unroll
    for (int off = 1; off < 64; off <<= 1) {
        s  += __shfl_xor(s,  off, 64);
        s2 += __shfl_xor(s2, off, 64);
    }
    __shared__ float red[8];
    int wv = tid >> 6;
    if ((tid & 63) == 0) { red[wv] = s; red[4 + wv] = s2; }
    __syncthreads();
    s  = red[0] + red[1] + red[2] + red[3];
    s2 = red[4] + red[5] + red[6] + red[7];
    float mu = s * (1.0f / H_DIM);
    float rs = rsqrtf(s2 * (1.0f / H_DIM) - mu * mu + 1e-5f);
    float4 wv4 = ((const float4*)w)[tid];
    float4 bv4 = ((const float4*)bb)[tid];
    ushort4 o;
    o.x = f32_bf16((v.x - mu) * rs * wv4.x + bv4.x);
    o.y = f32_bf16((v.y - mu) * rs * wv4.y + bv4.y);
    o.z = f32_bf16((v.z - mu) * rs * wv4.z + bv4.z);
    o.w = f32_bf16((v.w - mu) * rs * wv4.w + bv4.w);
    ((ushort4*)(out + (size_t)row * H_DIM))[tid] = o;
}

// ======== epilogue helper ========
template<int EPI>
static __device__ __forceinline__ void epi_store(f32x4 a, int row0, int col, int N,
                                                 const float* __restrict__ bias,
                                                 const float* __restrict__ resid,
                                                 float* __restrict__ outF,
                                                 unsigned short* __restrict__ outH,
                                                 unsigned short* __restrict__ outH2) {
    float bv = bias[col];
    if (EPI == 4 && col >= 2048) {
        int bb = row0 >> 11, ss = row0 & 2047;
        int hd = col - 2048;
        ushort4 u;
        u.x = f32_bf16(a[0] + bv);
        u.y = f32_bf16(a[1] + bv);
        u.z = f32_bf16(a[2] + bv);
        u.w = f32_bf16(a[3] + bv);
        *(ushort4*)&outH2[((size_t)bb * 1024 + hd) * SEQ + ss] = u;
    } else {
        #pragma unroll
        for (int j = 0; j < 4; ++j) {
            int row = row0 + j;
            size_t idx = (size_t)row * N + col;
            float c = a[j] + bv;
            if (EPI == 0) {
                outF[idx] = c;
            } else if (EPI == 1) {
                outF[idx] = resid[idx] + c;
            } else if (EPI == 2) {
                float g = 0.5f * c * (1.0f + fast_erf(c * 0.70710678118f));
                outH[idx] = f32_bf16(g);
            } else if (EPI == 3) {
                outH[idx] = f32_bf16(c);
            } else if (EPI == 5) {
                outH[idx] = f32_bf16(resid[idx] + c);
            } else if (EPI == 6) {
                outF[idx] = bf16_f32(outH2[idx]) + c;
            } else {
                float c2 = (col < 1024) ? c * QSCALE : c;
                outH[(size_t)row * 2048 + col] = f32_bf16(c2);
            }
        }
    }
}

// ---------------- bf16 MFMA GEMM, 128 x (NI*32) tile, BK=64, single-buffer,
//                  8 waves, wave-tile 64 x (NI*8); 2D XCD chunking ----------------
// Block mapping: XCD chunk c = bid&7 owns a (cm x cn) tile sub-grid; ncc = chunk-grid cols.
template<int EPI, int NI>
__global__ __launch_bounds__(512) void gemmT(const unsigned short* __restrict__ A,
                                             const unsigned short* __restrict__ Bt,
                                             const float* __restrict__ bias,
                                             const float* __restrict__ resid,
                                             float* __restrict__ outF,
                                             unsigned short* __restrict__ outH,
                                             unsigned short* __restrict__ outH2,
                                             int cm, int cn, int ncc, int N, int K) {
    constexpr int BN = NI * 32;
    constexpr int WN = BN / 4;
    constexpr int NT = WN / 16;
    __shared__ __attribute__((aligned(16))) unsigned short As[128][64];
    __shared__ __attribute__((aligned(16))) unsigned short Bs[BN][64];
    int tid = threadIdx.x;
    int w = tid >> 6, l = tid & 63;
    int l15 = l & 15, lg = l >> 4;
    int wm = w & 1, wn = w >> 1;

    int c = blockIdx.x & 7, lwg = blockIdx.x >> 3;
    int lm = lwg / cn, ln = lwg - lm * cn;
    int ccr = c / ncc;
    int bm = ccr * cm + lm;
    int bn = (c - ccr * ncc) * cn + ln;
    int m0 = bm * 128, n0 = bn * BN;

    f32x4 acc[4][NT] = {};

    const unsigned short* aptr[2];
    unsigned short* lA[2];
    #pragma unroll
    for (int j = 0; j < 2; ++j) {
        int slot = j * 512 + tid;
        int row = slot >> 3;
        int lchunk = (slot & 7) ^ (row & 7);
        aptr[j] = A + (size_t)(m0 + row) * K + lchunk * 8;
        lA[j] = &As[0][0] + (size_t)slot * 8 - l * 8;
    }
    const unsigned short* bptr[NI / 2];
    unsigned short* lB[NI / 2];
    #pragma unroll
    for (int j = 0; j < NI / 2; ++j) {
        int slot = j * 512 + tid;
        int row = slot >> 3;
        int lchunk = (slot & 7) ^ (row & 7);
        bptr[j] = Bt + (size_t)(n0 + row) * K + lchunk * 8;
        lB[j] = &Bs[0][0] + (size_t)slot * 8 - l * 8;
    }
    int swz[2];
    swz[0] = ((0 + lg) ^ (l15 & 7)) * 8;
    swz[1] = ((4 + lg) ^ (l15 & 7)) * 8;
    const unsigned short* pA = &As[wm * 64 + l15][0];
    const unsigned short* pB = &Bs[wn * WN + l15][0];

    for (int k0 = 0; k0 < K; k0 += 64) {
        __syncthreads();
        #pragma unroll
        for (int j = 0; j < 2; ++j) gload16(aptr[j] + k0, lA[j]);
        #pragma unroll
        for (int j = 0; j < NI / 2; ++j) gload16(bptr[j] + k0, lB[j]);
        __syncthreads();

        #pragma unroll
        for (int ks = 0; ks < 2; ++ks) {
            short8 af[4], bf[NT];
            #pragma unroll
            for (int mi = 0; mi < 4; ++mi)
                af[mi] = *(const short8*)(pA + mi * 16 * 64 + swz[ks]);
            #pragma unroll
            for (int ni = 0; ni < NT; ++ni)
                bf[ni] = *(const short8*)(pB + ni * 16 * 64 + swz[ks]);
            #pragma unroll
            for (int mi = 0; mi < 4; ++mi)
                #pragma unroll
                for (int ni = 0; ni < NT; ++ni)
                    acc[mi][ni] = __builtin_amdgcn_mfma_f32_16x16x32_bf16(af[mi], bf[ni], acc[mi][ni], 0, 0, 0);
        }
    }

    #pragma unroll
    for (int mi = 0; mi < 4; ++mi)
        #pragma unroll
        for (int ni = 0; ni < NT; ++ni)
            epi_store<EPI>(acc[mi][ni], m0 + wm * 64 + mi * 16 + lg * 4,
                           n0 + wn * WN + ni * 16 + l15, N, bias, resid, outF, outH, outH2);
}

// ---------------- causal flash attention: QBLK=64, 4 waves, PAIRED q-tiles (p, 31-p)
//                  -> uniform 33 KV-tile steps per block; dbuf + swizzle + all tricks ----
__global__ __launch_bounds__(256) void attn_mfma(const unsigned short* __restrict__ qk,
                                                 const unsigned short* __restrict__ vT,
                                                 unsigned short* __restrict__ out) {
    int bid = blockIdx.x;
    int swz = (bid & 7) * 64 + (bid >> 3);    // 512 % 8 == 0 -> bijective
    int b  = swz >> 8;
    int h  = (swz >> 4) & 15;
    int p  = swz & 15;                        // pair: q-tiles p and 31-p
    int tid = threadIdx.x;
    int w = tid >> 6, l = tid & 63;
    int l15 = l & 15, lg = l >> 4;

    __shared__ __attribute__((aligned(16))) unsigned short Ks[2][64][64];
    __shared__ __attribute__((aligned(16))) unsigned short Vt[2][64][64];
    __shared__ __attribute__((aligned(16))) unsigned short Ps[4][16][72];

    short8 vf5;
    #pragma unroll
    for (int i = 0; i < 8; ++i) vf5[i] = (l15 == 0) ? (short)0x3F80 : (short)0;

    // staging: 256 threads x 2 chunks each for K and V
    int sr = tid >> 2;                        // 0..63
    int c0 = (tid & 3) * 2, c1 = c0 + 1;      // logical chunks
    int sp0 = ((c0 ^ (sr & 7)) * 8);          // physical LDS cols
    int sp1 = ((c1 ^ (sr & 7)) * 8);
    const unsigned short* kb0 = qk + (size_t)(b * SEQ + sr) * 2048 + 1024 + h * DKV + c0 * 8;
    const unsigned short* kb1 = kb0 + 8;
    const unsigned short* vb0 = vT + ((size_t)(b * NHEAD + h) * DKV + sr) * SEQ + c0 * 8;
    const unsigned short* vb1 = vb0 + 8;

    int rk0 = ((0 + lg) ^ (l15 & 7)) * 8;
    int rk1 = ((4 + lg) ^ (l15 & 7)) * 8;

    auto run_pass = [&](int qt) {
        int qrow = qt * 64 + w * 16 + l15;
        const unsigned short* qp = qk + (size_t)(b * SEQ + qrow) * 2048 + h * DKV + lg * 8;
        short8 qf0 = *(const short8*)qp;
        short8 qf1 = *(const short8*)(qp + 32);
        float m = -1e30f;
        f32x4 oacc[4] = {};
        f32x4 oext = {};
        int nt = qt + 1;

        short8 kr0 = *(const short8*)kb0;
        short8 kr1 = *(const short8*)kb1;
        short8 vr0 = *(const short8*)vb0;
        short8 vr1 = *(const short8*)vb1;
        *(short8*)&Ks[0][sr][sp0] = kr0;
        *(short8*)&Ks[0][sr][sp1] = kr1;
        *(short8*)&Vt[0][sr][sp0] = vr0;
        *(short8*)&Vt[0][sr][sp1] = vr1;
        if (nt > 1) {
            kr0 = *(const short8*)(kb0 + (size_t)64 * 2048);
            kr1 = *(const short8*)(kb1 + (size_t)64 * 2048);
            vr0 = *(const short8*)(vb0 + 64);
            vr1 = *(const short8*)(vb1 + 64);
        }
        __syncthreads();

        for (int t = 0; t < nt; ++t) {
            int nb = (t + 1) & 1;
            if (t + 1 < nt) {
                *(short8*)&Ks[nb][sr][sp0] = kr0;
                *(short8*)&Ks[nb][sr][sp1] = kr1;
                *(short8*)&Vt[nb][sr][sp0] = vr0;
                *(short8*)&Vt[nb][sr][sp1] = vr1;
                if (t + 2 < nt) {
                    kr0 = *(const short8*)(kb0 + (size_t)(t + 2) * 64 * 2048);
                    kr1 = *(const short8*)(kb1 + (size_t)(t + 2) * 64 * 2048);
                    vr0 = *(const short8*)(vb0 + (t + 2) * 64);
                    vr1 = *(const short8*)(vb1 + (t + 2) * 64);
                }
            }
            int bu = t & 1;

            f32x4 sc[4] = {};
            __builtin_amdgcn_s_setprio(1);
            #pragma unroll
            for (int st = 0; st < 4; ++st) {
                short8 kf0 = *(const short8*)&Ks[bu][st * 16 + l15][rk0];
                sc[st] = __builtin_amdgcn_mfma_f32_16x16x32_bf16(kf0, qf0, sc[st], 0, 0, 0);
                short8 kf1 = *(const short8*)&Ks[bu][st * 16 + l15][rk1];
                sc[st] = __builtin_amdgcn_mfma_f32_16x16x32_bf16(kf1, qf1, sc[st], 0, 0, 0);
            }
            __builtin_amdgcn_s_setprio(0);

            float pv[4][4];
            float pmax = -1e30f;
            if (t == qt) {                    // only the diagonal tile masks
                int klim = qrow - t * 64;
                #pragma unroll
                for (int st = 0; st < 4; ++st) {
                    #pragma unroll
                    for (int j = 0; j < 4; ++j) {
                        float s = sc[st][j];
                        if (st * 16 + lg * 4 + j > klim) s = -1e30f;
                        pv[st][j] = s;
                        pmax = fmaxf(pmax, s);
                    }
                }
            } else {
                #pragma unroll
                for (int st = 0; st < 4; ++st) {
                    #pragma unroll
                    for (int j = 0; j < 4; ++j) {
                        pv[st][j] = sc[st][j];
                        pmax = fmaxf(pmax, sc[st][j]);
                    }
                }
            }

            if (!__all(pmax - m <= 8.0f)) {
                float pr = fmaxf(pmax, __shfl_xor(pmax, 16, 64));
                pr = fmaxf(pr, __shfl_xor(pr, 32, 64));
                float mn = fmaxf(m, pr);
                float scl2 = exp2f(m - mn);
                #pragma unroll
                for (int d = 0; d < 4; ++d)
                    #pragma unroll
                    for (int j = 0; j < 4; ++j)
                        oacc[d][j] *= scl2;
                #pragma unroll
                for (int j = 0; j < 4; ++j) oext[j] *= scl2;
                m = mn;
            }

            #pragma unroll
            for (int st = 0; st < 4; ++st) {
                float p0 = exp2f(pv[st][0] - m);
                float p1 = exp2f(pv[st][1] - m);
                float p2 = exp2f(pv[st][2] - m);
                float p3 = exp2f(pv[st][3] - m);
                unsigned int ua, ub;
                asm("v_cvt_pk_bf16_f32 %0, %1, %2" : "=v"(ua) : "v"(p0), "v"(p1));
                asm("v_cvt_pk_bf16_f32 %0, %1, %2" : "=v"(ub) : "v"(p2), "v"(p3));
                uint2 u = make_uint2(ua, ub);
                *(uint2*)&Ps[w][l15][st * 16 + lg * 4] = u;
            }

            __builtin_amdgcn_s_setprio(1);
            #pragma unroll
            for (int ks = 0; ks < 2; ++ks) {
                short8 pf = *(const short8*)&Ps[w][l15][ks * 32 + lg * 8];
                int rv = (ks == 0) ? rk0 : rk1;
                #pragma unroll
                for (int d = 0; d < 4; ++d) {
                    short8 vf = *(const short8*)&Vt[bu][d * 16 + l15][rv];
                    oacc[d] = __builtin_amdgcn_mfma_f32_16x16x32_bf16(vf, pf, oacc[d], 0, 0, 0);
                }
                oext = __builtin_amdgcn_mfma_f32_16x16x32_bf16(vf5, pf, oext, 0, 0, 0);
            }
            __builtin_amdgcn_s_setprio(0);
            __syncthreads();
        }

        float lsum = __shfl(oext[0], l15, 64);
        float inv = 1.0f / lsum;
        size_t ob = (size_t)(b * SEQ + qrow) * H_DIM + h * DKV;
        #pragma unroll
        for (int d = 0; d < 4; ++d) {
            ushort4 u;
            #pragma unroll
            for (int j = 0; j < 4; ++j)
                ((unsigned short*)&u)[j] = f32_bf16(oacc[d][j] * inv);
            *(ushort4*)&out[ob + d * 16 + lg * 4] = u;
        }
    };

    run_pass(31 - p);   // long half first
    run_pass(p);        // short half
}

// ---------------- launch ----------------
extern "C" void kernel_launch(void* const* d_in, const int* in_sizes, int n_in,
                              void* d_out, int out_size, void* d_ws, size_t ws_size,
                              hipStream_t stream) {
    const float* x     = (const float*)d_in[0];
    const float* ln1w  = (const float*)d_in[1];
    const float* ln1b  = (const float*)d_in[2];
    const float* Wqkv  = (const float*)d_in[3];
    const float* bqkv  = (const float*)d_in[4];
    const float* Wo    = (const float*)d_in[5];
    const float* bo    = (const float*)d_in[6];
    const float* ln2w  = (const float*)d_in[7];
    const float* ln2b  = (const float*)d_in[8];
    const float* Wfc   = (const float*)d_in[9];
    const float* bfc   = (const float*)d_in[10];
    const float* Wproj = (const float*)d_in[11];
    const float* bproj = (const float*)d_in[12];
    float* out = (float*)d_out;

    char* ws = (char*)d_ws;
    size_t off = 0;
    auto take = [&](size_t bytes) {
        void* p = ws + off;
        off += (bytes + 255) & ~(size_t)255;
        return p;
    };

    unsigned short* WqT  = (unsigned short*)take((size_t)3072 * 1024 * 2);
    unsigned short* WoT  = (unsigned short*)take((size_t)1024 * 1024 * 2);
    unsigned short* WfcT = (unsigned short*)take((size_t)4096 * 1024 * 2);
    unsigned short* WpT  = (unsigned short*)take((size_t)1024 * 4096 * 2);
    unsigned short* xn1   = (unsigned short*)take((size_t)ROWS * 1024 * 2);
    unsigned short* qk_h  = (unsigned short*)take((size_t)ROWS * 2048 * 2);
    unsigned short* vT    = (unsigned short*)take((size_t)ROWS * 1024 * 2);
    unsigned short* attn  = (unsigned short*)take((size_t)ROWS * 1024 * 2);
    unsigned short* x1h   = (unsigned short*)take((size_t)ROWS * 1024 * 2);
    unsigned short* xn2   = (unsigned short*)take((size_t)ROWS * 1024 * 2);
    unsigned short* hbuf  = (unsigned short*)take((size_t)ROWS * 4096 * 2);

    // weight transposes fp32[K][N] -> bf16[N][K]
    transpose_bf16<<<dim3(3072 / 32, 1024 / 32), 256, 0, stream>>>(Wqkv,  WqT,  1024, 3072);
    transpose_bf16<<<dim3(1024 / 32, 1024 / 32), 256, 0, stream>>>(Wo,    WoT,  1024, 1024);
    transpose_bf16<<<dim3(4096 / 32, 1024 / 32), 256, 0, stream>>>(Wfc,   WfcT, 1024, 4096);
    transpose_bf16<<<dim3(1024 / 32, 4096 / 32), 256, 0, stream>>>(Wproj, WpT,  4096, 1024);

    // LN1 (fp32 in) -> xn1
    ln_any<0><<<ROWS, 256, 0, stream>>>(x, ln1w, ln1b, xn1);

    // QKV: Q (pre-scaled) | K -> qk_h, V -> vT   (grid 768; XCD chunk 8x12)
    gemmT<4, 4><<<768, 512, 0, stream>>>(xn1, WqT, bqkv, nullptr, nullptr, qk_h, vT, 8, 12, 2, 3072, 1024);

    // causal attention -> attn (bf16), paired q-tiles, grid 512 x 256 thr
    attn_mfma<<<512, 256, 0, stream>>>(qk_h, vT, attn);

    // x1h = bf16(x + attn @ Wo + bo)   (XCD chunk 4x16 1D-equivalent)
    gemmT<5, 2><<<512, 512, 0, stream>>>(attn, WoT, bo, x, nullptr, x1h, nullptr, 4, 16, 1, 1024, 1024);

    // LN2 (bf16 in) -> xn2
    ln_any<1><<<ROWS, 256, 0, stream>>>(x1h, ln2w, ln2b, xn2);

    // h = gelu(xn2 @ Wfc + bfc)   (grid 1024; XCD chunk 8x16)
    gemmT<2, 4><<<1024, 512, 0, stream>>>(xn2, WfcT, bfc, nullptr, nullptr, hbuf, nullptr, 8, 16, 2, 4096, 1024);

    // out = x1h + h @ Wproj + bproj
    gemmT<6, 2><<<512, 512, 0, stream>>>(hbuf, WpT, bproj, nullptr, out, nullptr, x1h, 4, 16, 1, 1024, 4096);
}